// Round 10
// baseline (847.395 us; speedup 1.0000x reference)
//
#include <hip/hip_runtime.h>
#include <hip/hip_bf16.h>
#include <math.h>

#define B_   4
#define S_   4096
#define D_   1024
#define H_   16
#define M_   128
#define DH_  64
#define DFF_ 4096
#define BS_  (B_*S_)   // 16384 rows

typedef float  f32x4  __attribute__((ext_vector_type(4)));
typedef __bf16 bf16x8 __attribute__((ext_vector_type(8)));

__device__ __forceinline__ unsigned short f2bf(float f) {
    unsigned int u = __float_as_uint(f);
    u += 0x7FFFu + ((u >> 16) & 1u);     // round-to-nearest-even
    return (unsigned short)(u >> 16);
}
__device__ __forceinline__ float bf2f(unsigned short u) {
    return __uint_as_float((unsigned int)u << 16);
}

typedef __attribute__((address_space(1))) void void_g;
typedef __attribute__((address_space(3))) void void_l;
__device__ __forceinline__ void gl16(const void* g, void* l) {
    __builtin_amdgcn_global_load_lds((const void_g*)g, (void_l*)l, 16, 0, 0);
}

// XCD-chunked blockIdx swizzle (bijective when nwg % 8 == 0; identity otherwise)
__device__ __forceinline__ int xcd_swz(int bid, int nwg) {
    if (nwg & 7) return bid;
    return (bid & 7) * (nwg >> 3) + (bid >> 3);
}

#define QSCALE    0.35355339059327373f   // DH^-0.25
#define QSCALE2   0.125f                 // DH^-0.5
#define INVSQRTM  0.08838834764831845f   // 1/sqrt(128)

// ---------------------------------------------------------------------------
// Weight convert + transpose:  Wt[n][k] = bf16(W[k][n])
// ---------------------------------------------------------------------------
__global__ __launch_bounds__(256) void wconv_kernel(
    const float* __restrict__ W, unsigned short* __restrict__ Wt, int Kd, int Nd)
{
    __shared__ float ts[32][33];
    const int n0 = blockIdx.x * 32, k0 = blockIdx.y * 32;
    const int c = threadIdx.x & 31, rg = threadIdx.x >> 5;
#pragma unroll
    for (int i = 0; i < 4; ++i) {
        int r = rg * 4 + i;
        ts[r][c] = W[(size_t)(k0 + r) * Nd + n0 + c];
    }
    __syncthreads();
#pragma unroll
    for (int i = 0; i < 4; ++i) {
        int r = rg * 4 + i;
        Wt[(size_t)(n0 + r) * Kd + k0 + c] = f2bf(ts[c][r]);
    }
}

// x (f32) -> bf16, 8 elems/thread
__global__ __launch_bounds__(256) void x2bf_kernel(
    const float* __restrict__ in, unsigned short* __restrict__ o)
{
    const size_t i = ((size_t)blockIdx.x * 256 + threadIdx.x) * 8;
    const float4 a = *(const float4*)(in + i);
    const float4 b = *(const float4*)(in + i + 4);
    ushort4 p0, p1;
    p0.x = f2bf(a.x); p0.y = f2bf(a.y); p0.z = f2bf(a.z); p0.w = f2bf(a.w);
    p1.x = f2bf(b.x); p1.y = f2bf(b.y); p1.z = f2bf(b.z); p1.w = f2bf(b.w);
    *(ushort4*)(o + i) = p0;
    *(ushort4*)(o + i + 4) = p1;
}

// ---------------------------------------------------------------------------
// gemm256v3: 256x256 tile, BK=64, 8 waves, 128 KB LDS double-buffered.
// Counted vmcnt pipeline (T4): one half-tile prefetch per phase; per-phase
// waits vmcnt{6,6,6,8} (+barrier); last tile {4,2,0,0}. LDS rows PERMUTED so
// each staged half-tile is exactly what all 8 waves' next quadrant needs.
// Quadrant order (mh,nh): (0,0),(1,0),(1,1),(0,1); issue order A0,B0,A1,B1.
// Measured R9 (W1): 1155 TF, FETCH halved vs 2-phase, conflicts 0.
// EPI: 0 bias, 1 bias+res, 2 bias+ELU.  RBF: bf16 residual.  QKV: col routing.
// Output always bf16.
// ---------------------------------------------------------------------------
template<int EPI, bool RBF, bool QKV>
__global__ __launch_bounds__(512, 2) void gemm256v3_kernel(
    const unsigned short* __restrict__ A,
    const unsigned short* __restrict__ Bt,
    const float* __restrict__ b0, const float* __restrict__ b1,
    const float* __restrict__ b2,
    const void* __restrict__ resp,
    unsigned short* __restrict__ C0, unsigned short* __restrict__ C1,
    unsigned short* __restrict__ C2,
    int N, int K)
{
    extern __shared__ char lds[];
    const int t = threadIdx.x;
    const int l = t & 63;
    const int wid = t >> 6;
    const int wr = wid >> 2, wc = wid & 3;
    const int l15 = l & 15, l4 = l >> 4;

    const int nwg = gridDim.x * gridDim.y;
    const int bid = xcd_swz(blockIdx.y * gridDim.x + blockIdx.x, nwg);
    const int row0 = (bid / gridDim.x) * 256;
    const int col0 = (bid % gridDim.x) * 256;

    // staging source coords (pre-swizzled granule; permuted group->global rows)
    const int sRow = t >> 3;                       // 0..63 within a 64-row group
    const int sGran = (t & 7) ^ (sRow & 7);
    size_t aSrc[4], bSrc[4];
    {
        const int s5 = (sRow >> 5) << 6, r5 = sRow & 31;
#pragma unroll
        for (int g = 0; g < 4; ++g) {
            const int ga = ((g & 1) << 7) + ((g >> 1) << 6) + sRow;
            const int gb = ((g & 1) << 7) + ((g >> 1) << 5) + s5 + r5;
            aSrc[g] = (size_t)(row0 + ga) * K + sGran * 8;
            bSrc[g] = (size_t)(col0 + gb) * K + sGran * 8;
        }
    }

    // fragment-read constants (XOR granule swizzle; LDS row & 7 == l15 & 7)
    const int swz = l15 & 7;
    const int g0 = (l4 ^ swz) << 4;
    const int g1 = ((4 + l4) ^ swz) << 4;

    f32x4 acc[8][4] = {};
    const int NT = K >> 6;

    {   // prologue: tile 0 -> buf0 (A0,B0,A1,B1), full drain
        char* Ab = lds;
        char* Bb = lds + 65536;
        gl16(A + aSrc[0], (void*)(Ab + t * 16));
        gl16(A + aSrc[1], (void*)(Ab + 8192 + t * 16));
        gl16(Bt + bSrc[0], (void*)(Bb + t * 16));
        gl16(Bt + bSrc[1], (void*)(Bb + 8192 + t * 16));
        gl16(A + aSrc[2], (void*)(Ab + 16384 + t * 16));
        gl16(A + aSrc[3], (void*)(Ab + 24576 + t * 16));
        gl16(Bt + bSrc[2], (void*)(Bb + 16384 + t * 16));
        gl16(Bt + bSrc[3], (void*)(Bb + 24576 + t * 16));
        asm volatile("s_waitcnt vmcnt(0)" ::: "memory");
        asm volatile("s_barrier" ::: "memory");
    }

    for (int kt = 0; kt < NT; ++kt) {
        const char* Ab = lds + ((kt & 1) << 15);
        const char* Bb = lds + 65536 + ((kt & 1) << 15);
        char* nAb = lds + ((~kt & 1) << 15);
        char* nBb = lds + 65536 + ((~kt & 1) << 15);
        const size_t kOff = (size_t)(kt + 1) << 6;
        const bool pf = (kt + 1 < NT);

#pragma unroll
        for (int p = 0; p < 4; ++p) {
            const int mh = (p == 1 || p == 2) ? 1 : 0;   // (0,0),(1,0),(1,1),(0,1)
            const int nh = (p >> 1);
            if (pf) {
                if (p == 0) {
                    gl16(A + aSrc[0] + kOff, (void*)(nAb + t * 16));
                    gl16(A + aSrc[1] + kOff, (void*)(nAb + 8192 + t * 16));
                } else if (p == 1) {
                    gl16(Bt + bSrc[0] + kOff, (void*)(nBb + t * 16));
                    gl16(Bt + bSrc[1] + kOff, (void*)(nBb + 8192 + t * 16));
                } else if (p == 2) {
                    gl16(A + aSrc[2] + kOff, (void*)(nAb + 16384 + t * 16));
                    gl16(A + aSrc[3] + kOff, (void*)(nAb + 24576 + t * 16));
                } else {
                    gl16(Bt + bSrc[2] + kOff, (void*)(nBb + 16384 + t * 16));
                    gl16(Bt + bSrc[3] + kOff, (void*)(nBb + 24576 + t * 16));
                }
                if (p == 3) asm volatile("s_waitcnt vmcnt(8)" ::: "memory");
                else        asm volatile("s_waitcnt vmcnt(6)" ::: "memory");
            } else {
                if (p == 0)      asm volatile("s_waitcnt vmcnt(4)" ::: "memory");
                else if (p == 1) asm volatile("s_waitcnt vmcnt(2)" ::: "memory");
                else             asm volatile("s_waitcnt vmcnt(0)" ::: "memory");
            }
            asm volatile("s_barrier" ::: "memory");

            bf16x8 af[4][2], bfv[2][2];
            const int aBase = (mh * 128 + wr * 64 + l15) * 128;
            const int bBase = (nh * 128 + wc * 32 + l15) * 128;
#pragma unroll
            for (int mi = 0; mi < 4; ++mi) {
                af[mi][0] = *(const bf16x8*)(Ab + aBase + mi * 2048 + g0);
                af[mi][1] = *(const bf16x8*)(Ab + aBase + mi * 2048 + g1);
            }
#pragma unroll
            for (int ni = 0; ni < 2; ++ni) {
                bfv[ni][0] = *(const bf16x8*)(Bb + bBase + ni * 2048 + g0);
                bfv[ni][1] = *(const bf16x8*)(Bb + bBase + ni * 2048 + g1);
            }
            __builtin_amdgcn_s_setprio(1);
#pragma unroll
            for (int mi = 0; mi < 4; ++mi)
#pragma unroll
                for (int ni = 0; ni < 2; ++ni) {
                    acc[mh * 4 + mi][nh * 2 + ni] = __builtin_amdgcn_mfma_f32_16x16x32_bf16(
                        af[mi][0], bfv[ni][0], acc[mh * 4 + mi][nh * 2 + ni], 0, 0, 0);
                    acc[mh * 4 + mi][nh * 2 + ni] = __builtin_amdgcn_mfma_f32_16x16x32_bf16(
                        af[mi][1], bfv[ni][1], acc[mh * 4 + mi][nh * 2 + ni], 0, 0, 0);
                }
            __builtin_amdgcn_s_setprio(0);
            asm volatile("s_barrier" ::: "memory");
        }
    }

    // epilogue (bf16 out; QKV routes 1024-col groups to C0/C1/C2)
    const int sel = QKV ? (col0 >> 10) : 0;
    const float* bias = QKV ? (sel == 0 ? b0 : (sel == 1 ? b1 : b2)) : b0;
    unsigned short* ob = QKV ? (sel == 0 ? C0 : (sel == 1 ? C1 : C2)) : C0;
    const int colLoc0 = (QKV ? (col0 & 1023) : col0) + wc * 64;
    const int ostr = QKV ? 1024 : N;

#pragma unroll
    for (int ni = 0; ni < 4; ++ni) {
        const int col = colLoc0 + ni * 16 + l15;
        const float bc = bias[col];
#pragma unroll
        for (int mi = 0; mi < 8; ++mi) {
#pragma unroll
            for (int r = 0; r < 4; ++r) {
                const int row = row0 + wr * 128 + mi * 16 + l4 * 4 + r;
                float v = acc[mi][ni][r] + bc;
                if (EPI == 1) {
                    if (RBF) v += bf2f(((const unsigned short*)resp)[(size_t)row * ostr + col]);
                    else     v += ((const float*)resp)[(size_t)row * ostr + col];
                }
                if (EPI == 2) v = v > 0.f ? v : expm1f(v);
                ob[(size_t)row * ostr + col] = f2bf(v);
            }
        }
    }
}

// ---------------------------------------------------------------------------
// 128x128 2-phase GEMM (exact R6 structure, no swizzle) - ws-tight QKV fallback
// ---------------------------------------------------------------------------
template<int EPI, bool AF32, bool OBF, bool RBF>
__global__ __launch_bounds__(256, 4) void gemm_kernel(
    const void* __restrict__ Ap,
    const unsigned short* __restrict__ Bt,
    const float* __restrict__ bias,
    const void* __restrict__ resp,
    void* __restrict__ Cp,
    int N, int K)
{
    __shared__ __align__(16) char AsRaw[AF32 ? 32768 : 16384];
    __shared__ __align__(16) char BsRaw[16384];

    const int t = threadIdx.x;
    const int lane = t & 63;
    const int wv = t >> 6;
    const int wr = wv >> 1, wc = wv & 1;
    const int row0 = blockIdx.y * 128;
    const int col0 = blockIdx.x * 128;
    const int l15 = lane & 15, l4 = lane >> 4;

    const int bRow = t >> 3;
    const int bGran = (t & 7) ^ ((t >> 3) & 7);
    const int aRowF = t >> 4;
    const int aGranF = (t & 15) ^ ((t >> 4) & 15);

    f32x4 acc[4][4] = {};

    for (int k0 = 0; k0 < K; k0 += 64) {
#pragma unroll
        for (int r = 0; r < 4; ++r) {
            const int row = r * 32 + bRow;
            gl16(Bt + (size_t)(col0 + row) * K + k0 + bGran * 8,
                 (void*)(BsRaw + r * 4096 + t * 16));
        }
        if (AF32) {
            const float* A = (const float*)Ap;
#pragma unroll
            for (int r = 0; r < 8; ++r) {
                const int row = r * 16 + aRowF;
                gl16(A + (size_t)(row0 + row) * K + k0 + aGranF * 4,
                     (void*)(AsRaw + r * 4096 + t * 16));
            }
        } else {
            const unsigned short* A = (const unsigned short*)Ap;
#pragma unroll
            for (int r = 0; r < 4; ++r) {
                const int row = r * 32 + bRow;
                gl16(A + (size_t)(row0 + row) * K + k0 + bGran * 8,
                     (void*)(AsRaw + r * 4096 + t * 16));
            }
        }
        __syncthreads();

#pragma unroll
        for (int ks = 0; ks < 2; ++ks) {
            bf16x8 af[4], bfv[4];
            if (AF32) {
#pragma unroll
                for (int mi = 0; mi < 4; ++mi) {
                    const int row = wr * 64 + mi * 16 + l15;
                    const int sw = (row & 15) << 4;
                    const float4 x0 = *(const float4*)(AsRaw + row * 256 + ((ks * 128 + l4 * 32) ^ sw));
                    const float4 x1 = *(const float4*)(AsRaw + row * 256 + ((ks * 128 + l4 * 32 + 16) ^ sw));
                    bf16x8 v;
                    v[0] = (__bf16)x0.x; v[1] = (__bf16)x0.y;
                    v[2] = (__bf16)x0.z; v[3] = (__bf16)x0.w;
                    v[4] = (__bf16)x1.x; v[5] = (__bf16)x1.y;
                    v[6] = (__bf16)x1.z; v[7] = (__bf16)x1.w;
                    af[mi] = v;
                }
            } else {
#pragma unroll
                for (int mi = 0; mi < 4; ++mi) {
                    const int row = wr * 64 + mi * 16 + l15;
                    af[mi] = *(const bf16x8*)(AsRaw + row * 128 + ((ks * 64 + l4 * 16) ^ ((row & 7) << 4)));
                }
            }
#pragma unroll
            for (int ni = 0; ni < 4; ++ni) {
                const int row = wc * 64 + ni * 16 + l15;
                bfv[ni] = *(const bf16x8*)(BsRaw + row * 128 + ((ks * 64 + l4 * 16) ^ ((row & 7) << 4)));
            }
#pragma unroll
            for (int mi = 0; mi < 4; ++mi)
#pragma unroll
                for (int ni = 0; ni < 4; ++ni)
                    acc[mi][ni] = __builtin_amdgcn_mfma_f32_16x16x32_bf16(
                        af[mi], bfv[ni], acc[mi][ni], 0, 0, 0);
        }
        __syncthreads();
    }

#pragma unroll
    for (int ni = 0; ni < 4; ++ni) {
        const int col = col0 + wc * 64 + ni * 16 + l15;
        const float bc = bias[col];
#pragma unroll
        for (int mi = 0; mi < 4; ++mi) {
#pragma unroll
            for (int r = 0; r < 4; ++r) {
                const int row = row0 + wr * 64 + mi * 16 + l4 * 4 + r;
                float v = acc[mi][ni][r] + bc;
                if (EPI == 1) {
                    if (RBF) v += bf2f(((const unsigned short*)resp)[(size_t)row * N + col]);
                    else     v += ((const float*)resp)[(size_t)row * N + col];
                }
                if (EPI == 2) v = v > 0.f ? v : expm1f(v);
                if (OBF) ((unsigned short*)Cp)[(size_t)row * N + col] = f2bf(v);
                else     ((float*)Cp)[(size_t)row * N + col] = v;
            }
        }
    }
}

// ---------------------------------------------------------------------------
// kv kernel (MFMA): per (bh, chunk of 512 rows), 8 sub-tiles of 64 rows.
// ---------------------------------------------------------------------------
__global__ __launch_bounds__(256) void kv_mfma_kernel(
    const unsigned short* __restrict__ Kmat,
    const unsigned short* __restrict__ Vmat,
    const float* __restrict__ omega,
    float* __restrict__ kvp)
{
    __shared__ unsigned short omegaB[128][72];
    __shared__ union U2 {
        unsigned short kA[64][72];
        unsigned short vT[80 * 64];
    } u2;
    __shared__ unsigned short pk[64][130];
    __shared__ float sqp[256];
    __shared__ float sqk[64];

    const int bh = blockIdx.x, chunk = blockIdx.y;
    const int b = bh >> 4, h = bh & 15;
    const int t = threadIdx.x, l = t & 63, w = t >> 6;
    const int l15 = l & 15, l4 = l >> 4;
    const int srow0 = b * S_ + chunk * 512;

    {
        const int m = t >> 1, d0 = (t & 1) * 32;
        const float* src = omega + m * 64 + d0;
#pragma unroll
        for (int i = 0; i < 8; ++i) {
            float4 v4 = *(const float4*)(src + i * 4);
            ushort4 p;
            p.x = f2bf(v4.x * QSCALE); p.y = f2bf(v4.y * QSCALE);
            p.z = f2bf(v4.z * QSCALE); p.w = f2bf(v4.w * QSCALE);
            *(ushort4*)&omegaB[m][d0 + i * 4] = p;
        }
    }

    f32x4 akv[5][2] = {};

    for (int sub = 0; sub < 8; ++sub) {
        {
            const int r = t >> 2, d0 = (t & 3) * 16;
            const unsigned short* src = Kmat + (size_t)(srow0 + sub * 64 + r) * D_ + h * 64 + d0;
            uint4 v0 = *(const uint4*)src;
            uint4 v1 = *(const uint4*)(src + 8);
            *(uint4*)&u2.kA[r][d0] = v0;
            *(uint4*)&u2.kA[r][d0 + 8] = v1;
            float a = 0.f;
            const unsigned short* pv = (const unsigned short*)&v0;
#pragma unroll
            for (int j = 0; j < 8; ++j) { float f = bf2f(pv[j]); a += f * f; }
            pv = (const unsigned short*)&v1;
#pragma unroll
            for (int j = 0; j < 8; ++j) { float f = bf2f(pv[j]); a += f * f; }
            sqp[t] = a;
        }
        __syncthreads();
        if (t < 64)
            sqk[t] = (sqp[4 * t] + sqp[4 * t + 1] + sqp[4 * t + 2] + sqp[4 * t + 3]) * (QSCALE2 * 0.5f);
        f32x4 a1[8] = {};
#pragma unroll
        for (int ks = 0; ks < 2; ++ks) {
            bf16x8 af = *(const bf16x8*)&u2.kA[w * 16 + l15][ks * 32 + l4 * 8];
            bf16x8 bf[8];
#pragma unroll
            for (int ni = 0; ni < 8; ++ni)
                bf[ni] = *(const bf16x8*)&omegaB[ni * 16 + l15][ks * 32 + l4 * 8];
#pragma unroll
            for (int ni = 0; ni < 8; ++ni)
                a1[ni] = __builtin_amdgcn_mfma_f32_16x16x32_bf16(af, bf[ni], a1[ni], 0, 0, 0);
        }
        __syncthreads();
#pragma unroll
        for (int ni = 0; ni < 8; ++ni)
#pragma unroll
            for (int r = 0; r < 4; ++r) {
                int row = w * 16 + l4 * 4 + r;
                float p = expf(a1[ni][r] - sqk[row]) * INVSQRTM + 1e-6f;
                pk[row][ni * 16 + l15] = f2bf(p);
            }
        {
            const int s = t >> 2, d0 = (t & 3) * 16;
            const unsigned short* src = Vmat + (size_t)(srow0 + sub * 64 + s) * D_ + h * 64 + d0;
            uint4 v0 = *(const uint4*)src;
            uint4 v1 = *(const uint4*)(src + 8);
            unsigned short tmp[16];
            *(uint4*)&tmp[0] = v0; *(uint4*)&tmp[8] = v1;
            char* vb = (char*)u2.vT;
#pragma unroll
            for (int j = 0; j < 16; ++j) {
                int d = d0 + j;
                int byte = (d * 128 + s * 2) ^ ((d & 7) << 4);
                *(unsigned short*)(vb + byte) = tmp[j];
            }
        }
        if (t < 128) {
            int row = 64 + (t >> 3), s0 = (t & 7) * 8;
            unsigned short val = (row == 64) ? (unsigned short)0x3F80 : (unsigned short)0;
            char* vb = (char*)u2.vT;
#pragma unroll
            for (int j = 0; j < 8; ++j) {
                int byte = (row * 128 + (s0 + j) * 2) ^ ((row & 7) << 4);
                *(unsigned short*)(vb + byte) = val;
            }
        }
        __syncthreads();
#pragma unroll
        for (int ks = 0; ks < 2; ++ks) {
            bf16x8 af[5];
            const char* vb = (const char*)u2.vT;
#pragma unroll
            for (int at = 0; at < 5; ++at) {
                int d = at * 16 + l15;
                int byte = (d * 128 + (ks * 32 + l4 * 8) * 2) ^ ((d & 7) << 4);
                af[at] = *(const bf16x8*)(vb + byte);
            }
            bf16x8 bfr[2];
#pragma unroll
            for (int nt = 0; nt < 2; ++nt) {
                unsigned short tmp[8];
#pragma unroll
                for (int j = 0; j < 8; ++j)
                    tmp[j] = pk[ks * 32 + l4 * 8 + j][w * 32 + nt * 16 + l15];
                bfr[nt] = *(const bf16x8*)tmp;
            }
#pragma unroll
            for (int at = 0; at < 5; ++at)
#pragma unroll
                for (int nt = 0; nt < 2; ++nt)
                    akv[at][nt] = __builtin_amdgcn_mfma_f32_16x16x32_bf16(af[at], bfr[nt], akv[at][nt], 0, 0, 0);
        }
        __syncthreads();
    }

    const size_t base = ((size_t)chunk * 64 + bh) * (80 * 128);
#pragma unroll
    for (int at = 0; at < 5; ++at)
#pragma unroll
        for (int nt = 0; nt < 2; ++nt)
#pragma unroll
            for (int r = 0; r < 4; ++r) {
                int row = at * 16 + l4 * 4 + r;
                int col = w * 32 + nt * 16 + l15;
                kvp[base + (size_t)row * 128 + col] = akv[at][nt][r];
            }
}

__global__ __launch_bounds__(256) void kvt_reduce_kernel(
    const float* __restrict__ kvp, unsigned short* __restrict__ kvT)
{
    const int idx = blockIdx.x * 256 + threadIdx.x;
    const int NKV = 64 * 80 * 128;
    float s = 0.f;
#pragma unroll
    for (int c = 0; c < 8; ++c) s += kvp[(size_t)c * NKV + idx];
    kvT[idx] = f2bf(s);
}

// ---------------------------------------------------------------------------
// attn kernel (MFMA): per (bh, 128-row tile).
// ---------------------------------------------------------------------------
__global__ __launch_bounds__(256) void attn_mfma_kernel(
    const unsigned short* __restrict__ Qmat,
    const float* __restrict__ omega,
    const unsigned short* __restrict__ kvT,
    unsigned short* __restrict__ attn)
{
    __shared__ union U {
        struct { unsigned short omegaB[128][72]; unsigned short qA[128][72]; } s1;
        struct { unsigned short pq[128][136]; } s2;
    } u;
    __shared__ unsigned short kvB[80][136];
    __shared__ float sqp[256];
    __shared__ float sqr[128];
    __shared__ float zden[128];

    const int bh = blockIdx.x, sc = blockIdx.y;
    const int b = bh >> 4, h = bh & 15;
    const int t = threadIdx.x, l = t & 63, w = t >> 6;
    const int l15 = l & 15, l4 = l >> 4;
    const int srow0 = b * S_ + sc * 128;

    {
        const int m = t >> 1, d0 = (t & 1) * 32;
        const float* src = omega + m * 64 + d0;
#pragma unroll
        for (int i = 0; i < 8; ++i) {
            float4 v4 = *(const float4*)(src + i * 4);
            ushort4 p;
            p.x = f2bf(v4.x * QSCALE); p.y = f2bf(v4.y * QSCALE);
            p.z = f2bf(v4.z * QSCALE); p.w = f2bf(v4.w * QSCALE);
            *(ushort4*)&u.s1.omegaB[m][d0 + i * 4] = p;
        }
    }
    if (t < 160) {
        const int rr = t >> 1, c0 = (t & 1) * 64;
        const uint4* src = (const uint4*)(kvT + ((size_t)bh * 80 + rr) * 128 + c0);
#pragma unroll
        for (int i = 0; i < 8; ++i)
            *(uint4*)&kvB[rr][c0 + i * 8] = src[i];
    }
    {
        const int r = t >> 1, d0 = (t & 1) * 32;
        const unsigned short* src = Qmat + (size_t)(srow0 + r) * D_ + h * 64 + d0;
        float a = 0.f;
#pragma unroll
        for (int i = 0; i < 4; ++i) {
            uint4 v8 = *(const uint4*)(src + i * 8);
            *(uint4*)&u.s1.qA[r][d0 + i * 8] = v8;
            const unsigned short* pv = (const unsigned short*)&v8;
#pragma unroll
            for (int j = 0; j < 8; ++j) { float f = bf2f(pv[j]); a += f * f; }
        }
        sqp[t] = a;
    }
    __syncthreads();
    if (t < 128) sqr[t] = (sqp[2 * t] + sqp[2 * t + 1]) * (QSCALE2 * 0.5f);

    f32x4 acc1[2][8] = {};
#pragma unroll
    for (int ks = 0; ks < 2; ++ks) {
        bf16x8 af[2], bf[8];
#pragma unroll
        for (int mi = 0; mi < 2; ++mi)
            af[mi] = *(const bf16x8*)&u.s1.qA[w * 32 + mi * 16 + l15][ks * 32 + l4 * 8];
#pragma unroll
        for (int ni = 0; ni < 8; ++ni)
            bf[ni] = *(const bf16x8*)&u.s1.omegaB[ni * 16 + l15][ks * 32 + l4 * 8];
#pragma unroll
        for (int mi = 0; mi < 2; ++mi)
#pragma unroll
            for (int ni = 0; ni < 8; ++ni)
                acc1[mi][ni] = __builtin_amdgcn_mfma_f32_16x16x32_bf16(af[mi], bf[ni], acc1[mi][ni], 0, 0, 0);
    }
    __syncthreads();

#pragma unroll
    for (int mi = 0; mi < 2; ++mi)
#pragma unroll
        for (int ni = 0; ni < 8; ++ni)
#pragma unroll
            for (int r = 0; r < 4; ++r) {
                int row = w * 32 + mi * 16 + l4 * 4 + r;
                float p = expf(acc1[mi][ni][r] - sqr[row]) * INVSQRTM + 1e-6f;
                u.s2.pq[row][ni * 16 + l15] = f2bf(p);
            }
    __syncthreads();

    f32x4 acc2[2][5] = {};
#pragma unroll
    for (int ks = 0; ks < 4; ++ks) {
        bf16x8 af[2], bf[5];
#pragma unroll
        for (int mi = 0; mi < 2; ++mi)
            af[mi] = *(const bf16x8*)&u.s2.pq[w * 32 + mi * 16 + l15][ks * 32 + l4 * 8];
#pragma unroll
        for (int ni = 0; ni < 5; ++ni)
            bf[ni] = *(const bf16x8*)&kvB[ni * 16 + l15][ks * 32 + l4 * 8];
#pragma unroll
        for (int mi = 0; mi < 2; ++mi)
#pragma unroll
            for (int ni = 0; ni < 5; ++ni)
                acc2[mi][ni] = __builtin_amdgcn_mfma_f32_16x16x32_bf16(af[mi], bf[ni], acc2[mi][ni], 0, 0, 0);
    }
    if (l15 == 0) {
#pragma unroll
        for (int mi = 0; mi < 2; ++mi)
#pragma unroll
            for (int r = 0; r < 4; ++r) {
                int row = w * 32 + mi * 16 + l4 * 4 + r;
                zden[row] = 1.f / (acc2[mi][4][r] + 1e-6f);
            }
    }
    __syncthreads();
#pragma unroll
    for (int ni = 0; ni < 4; ++ni)
#pragma unroll
        for (int mi = 0; mi < 2; ++mi)
#pragma unroll
            for (int r = 0; r < 4; ++r) {
                int row = w * 32 + mi * 16 + l4 * 4 + r;
                float o = acc2[mi][ni][r] * zden[row];
                attn[(size_t)(srow0 + row) * D_ + h * 64 + ni * 16 + l15] = f2bf(o);
            }
}

// ---------------------------------------------------------------------------
// LayerNorm over D_=1024, one row per block.
// ---------------------------------------------------------------------------
template<bool INBF, bool OUTBF>
__global__ __launch_bounds__(256) void layernorm_kernel(
    const void* __restrict__ inp, const float* __restrict__ g,
    const float* __restrict__ be, void* __restrict__ outp)
{
    const int row = blockIdx.x;
    const int t = threadIdx.x;
    const int l = t & 63, w = t >> 6;
    float4 v;
    if (INBF) {
        const ushort4 r4 = *(const ushort4*)((const unsigned short*)inp + (size_t)row * D_ + t * 4);
        v.x = bf2f(r4.x); v.y = bf2f(r4.y); v.z = bf2f(r4.z); v.w = bf2f(r4.w);
    } else {
        v = *(const float4*)((const float*)inp + (size_t)row * D_ + t * 4);
    }
    float s = v.x + v.y + v.z + v.w;
    float ss = v.x * v.x + v.y * v.y + v.z * v.z + v.w * v.w;
#pragma unroll
    for (int o = 32; o > 0; o >>= 1) { s += __shfl_xor(s, o); ss += __shfl_xor(ss, o); }
    __shared__ float red[8];
    if (l == 0) { red[w] = s; red[4 + w] = ss; }
    __syncthreads();
    s = red[0] + red[1] + red[2] + red[3];
    ss = red[4] + red[5] + red[6] + red[7];
    const float mu = s * (1.f / D_);
    const float var = ss * (1.f / D_) - mu * mu;
    const float r = rsqrtf(var + 1e-6f);
    const float4 gg = *(const float4*)(g + t * 4);
    const float4 bb = *(const float4*)(be + t * 4);
    float4 o4;
    o4.x = (v.x - mu) * r * gg.x + bb.x;
    o4.y = (v.y - mu) * r * gg.y + bb.y;
    o4.z = (v.z - mu) * r * gg.z + bb.z;
    o4.w = (v.w - mu) * r * gg.w + bb.w;
    if (OUTBF) {
        ushort4 p;
        p.x = f2bf(o4.x); p.y = f2bf(o4.y); p.z = f2bf(o4.z); p.w = f2bf(o4.w);
        *(ushort4*)((unsigned short*)outp + (size_t)row * D_ + t * 4) = p;
    } else {
        *(float4*)((float*)outp + (size_t)row * D_ + t * 4) = o4;
    }
}

// ---------------------------------------------------------------------------
extern "C" void kernel_launch(void* const* d_in, const int* in_sizes, int n_in,
                              void* d_out, int out_size, void* d_ws, size_t ws_size,
                              hipStream_t stream)
{
    (void)in_sizes; (void)n_in; (void)out_size;
    const float* x     = (const float*)d_in[0];
    const float* Wq    = (const float*)d_in[1];
    const float* bq    = (const float*)d_in[2];
    const float* Wk    = (const float*)d_in[3];
    const float* bk    = (const float*)d_in[4];
    const float* Wv    = (const float*)d_in[5];
    const float* bv    = (const float*)d_in[6];
    const float* Wo    = (const float*)d_in[7];
    const float* bo    = (const float*)d_in[8];
    const float* omega = (const float*)d_in[9];
    const float* W1    = (const float*)d_in[10];
    const float* b1    = (const float*)d_in[11];
    const float* W2    = (const float*)d_in[12];
    const float* b2    = (const float*)d_in[13];
    const float* g1    = (const float*)d_in[14];
    const float* be1   = (const float*)d_in[15];
    const float* g2    = (const float*)d_in[16];
    const float* be2   = (const float*)d_in[17];
    float* out = (float*)d_out;

    const int LDSZ = 131072;
    {
        auto kQ = gemm256v3_kernel<0, false, true>;
        auto kR = gemm256v3_kernel<1, false, false>;
        auto kE = gemm256v3_kernel<2, false, false>;
        auto kB = gemm256v3_kernel<1, true, false>;
        (void)hipFuncSetAttribute((const void*)kQ, hipFuncAttributeMaxDynamicSharedMemorySize, LDSZ);
        (void)hipFuncSetAttribute((const void*)kR, hipFuncAttributeMaxDynamicSharedMemorySize, LDSZ);
        (void)hipFuncSetAttribute((const void*)kE, hipFuncAttributeMaxDynamicSharedMemorySize, LDSZ);
        (void)hipFuncSetAttribute((const void*)kB, hipFuncAttributeMaxDynamicSharedMemorySize, LDSZ);
    }

    const size_t ACT = (size_t)BS_ * D_;
    unsigned short* slotQ = (unsigned short*)d_ws;
    unsigned short* slotK = slotQ + ACT;
    unsigned short* slotV = slotK + ACT;
    float* kvp = (float*)(slotV + ACT);
    unsigned short* kvT = (unsigned short*)(kvp + (size_t)8 * 64 * 80 * 128);
    unsigned short* Wqkvt = kvT + (size_t)64 * 80 * 128;
    unsigned short* Wot = Wqkvt + (size_t)3 * D_ * D_;
    unsigned short* W1t = Wot + (size_t)D_ * D_;
    unsigned short* W2t = W1t + (size_t)D_ * DFF_;
    unsigned short* wsEnd = W2t + (size_t)DFF_ * D_;

    const size_t fixedBytes = (size_t)((char*)wsEnd - (char*)d_ws);
    char* cur = (char*)wsEnd;

    const bool useFused = ws_size >= fixedBytes + ACT * 2;
    unsigned short* xbf = nullptr;
    if (useFused) { xbf = (unsigned short*)cur; cur += ACT * 2; }
    const size_t usedBytes = (size_t)(cur - (char*)d_ws);

    int nch;
    unsigned short* ffn1;
    if (ws_size >= usedBytes + (size_t)BS_ * DFF_ * 2) {
        nch = 1;  ffn1 = (unsigned short*)cur;
    } else if (ws_size >= usedBytes + (size_t)(BS_ / 2) * DFF_ * 2) {
        nch = 2;  ffn1 = (unsigned short*)cur;
    } else {
        nch = 4;  ffn1 = slotK;
    }

    unsigned short* attn = slotK;
    unsigned short* tmp1 = slotV;
    unsigned short* out1 = slotQ;
    unsigned short* tmp2 = slotV;

    // 1. weights -> bf16 transposed (Wq/Wk/Wv concatenated along n)
    wconv_kernel<<<dim3(D_ / 32, D_ / 32), 256, 0, stream>>>(Wq, Wqkvt, D_, D_);
    wconv_kernel<<<dim3(D_ / 32, D_ / 32), 256, 0, stream>>>(Wk, Wqkvt + (size_t)D_ * D_, D_, D_);
    wconv_kernel<<<dim3(D_ / 32, D_ / 32), 256, 0, stream>>>(Wv, Wqkvt + (size_t)2 * D_ * D_, D_, D_);
    wconv_kernel<<<dim3(D_ / 32, D_ / 32), 256, 0, stream>>>(Wo, Wot, D_, D_);
    wconv_kernel<<<dim3(DFF_ / 32, D_ / 32), 256, 0, stream>>>(W1, W1t, D_, DFF_);
    wconv_kernel<<<dim3(D_ / 32, DFF_ / 32), 256, 0, stream>>>(W2, W2t, DFF_, D_);

    // 2. Q,K,V projections (fused v3; 128^2 AF32 fallback if ws tight)
    if (useFused) {
        x2bf_kernel<<<dim3(BS_ * D_ / 2048), 256, 0, stream>>>(x, xbf);
        gemm256v3_kernel<0, false, true><<<dim3(3 * D_ / 256, BS_ / 256), 512, LDSZ, stream>>>(
            xbf, Wqkvt, bq, bk, bv, nullptr, slotQ, slotK, slotV, 3 * D_, D_);
    } else {
        gemm_kernel<0, true, true, false><<<dim3(D_ / 128, BS_ / 128), 256, 0, stream>>>(x, Wqkvt, bq, nullptr, slotQ, D_, D_);
        gemm_kernel<0, true, true, false><<<dim3(D_ / 128, BS_ / 128), 256, 0, stream>>>(x, Wqkvt + (size_t)D_ * D_, bk, nullptr, slotK, D_, D_);
        gemm_kernel<0, true, true, false><<<dim3(D_ / 128, BS_ / 128), 256, 0, stream>>>(x, Wqkvt + (size_t)2 * D_ * D_, bv, nullptr, slotV, D_, D_);
    }

    // 3. phi(k) -> kvT_aug partials -> reduce to bf16
    kv_mfma_kernel<<<dim3(64, 8), 256, 0, stream>>>(slotK, slotV, omega, kvp);
    kvt_reduce_kernel<<<dim3(2560), 256, 0, stream>>>(kvp, kvT);

    // 4. phi(q) -> normalized attention (bf16, overwrites k slot)
    attn_mfma_kernel<<<dim3(64, 32), 256, 0, stream>>>(slotQ, omega, kvT, attn);

    // 5. Wo projection + residual(x f32) -> tmp1 (v3); LN -> out1
    gemm256v3_kernel<1, false, false><<<dim3(D_ / 256, BS_ / 256), 512, LDSZ, stream>>>(
        attn, Wot, bo, nullptr, nullptr, x, tmp1, nullptr, nullptr, D_, D_);
    layernorm_kernel<true, true><<<dim3(BS_), 256, 0, stream>>>(tmp1, g1, be1, out1);

    // 6. FFN in nch row-chunks (both GEMMs on v3)
    const int rows = BS_ / nch;
    for (int c = 0; c < nch; ++c) {
        const size_t off = (size_t)c * rows * D_;
        gemm256v3_kernel<2, false, false><<<dim3(DFF_ / 256, rows / 256), 512, LDSZ, stream>>>(
            out1 + off, W1t, b1, nullptr, nullptr, nullptr, ffn1, nullptr, nullptr, DFF_, D_);
        gemm256v3_kernel<1, true, false><<<dim3(D_ / 256, rows / 256), 512, LDSZ, stream>>>(
            ffn1, W2t, b2, nullptr, nullptr, out1 + off, tmp2 + off, nullptr, nullptr, D_, DFF_);
    }

    // 7. LN2 -> out (f32)
    layernorm_kernel<true, false><<<dim3(BS_), 256, 0, stream>>>(tmp2, g2, be2, out);
}

// Round 11
// 668.101 us; speedup vs baseline: 1.2684x; 1.2684x over previous
//
#include <hip/hip_runtime.h>
#include <hip/hip_bf16.h>
#include <math.h>

#define B_   4
#define S_   4096
#define D_   1024
#define H_   16
#define M_   128
#define DH_  64
#define DFF_ 4096
#define BS_  (B_*S_)   // 16384 rows

typedef float  f32x4  __attribute__((ext_vector_type(4)));
typedef __bf16 bf16x8 __attribute__((ext_vector_type(8)));

__device__ __forceinline__ unsigned short f2bf(float f) {
    unsigned int u = __float_as_uint(f);
    u += 0x7FFFu + ((u >> 16) & 1u);     // round-to-nearest-even
    return (unsigned short)(u >> 16);
}
__device__ __forceinline__ float bf2f(unsigned short u) {
    return __uint_as_float((unsigned int)u << 16);
}

typedef __attribute__((address_space(1))) void void_g;
typedef __attribute__((address_space(3))) void void_l;
__device__ __forceinline__ void gl16(const void* g, void* l) {
    __builtin_amdgcn_global_load_lds((const void_g*)g, (void_l*)l, 16, 0, 0);
}

#define QSCALE    0.35355339059327373f   // DH^-0.25
#define QSCALE2   0.125f                 // DH^-0.5
#define INVSQRTM  0.08838834764831845f   // 1/sqrt(128)

// ---------------------------------------------------------------------------
// Weight convert + transpose:  Wt[n][k] = bf16(W[k][n])
// ---------------------------------------------------------------------------
__global__ __launch_bounds__(256) void wconv_kernel(
    const float* __restrict__ W, unsigned short* __restrict__ Wt, int Kd, int Nd)
{
    __shared__ float ts[32][33];
    const int n0 = blockIdx.x * 32, k0 = blockIdx.y * 32;
    const int c = threadIdx.x & 31, rg = threadIdx.x >> 5;
#pragma unroll
    for (int i = 0; i < 4; ++i) {
        int r = rg * 4 + i;
        ts[r][c] = W[(size_t)(k0 + r) * Nd + n0 + c];
    }
    __syncthreads();
#pragma unroll
    for (int i = 0; i < 4; ++i) {
        int r = rg * 4 + i;
        Wt[(size_t)(n0 + r) * Kd + k0 + c] = f2bf(ts[c][r]);
    }
}

// x (f32) -> bf16, 8 elems/thread
__global__ __launch_bounds__(256) void x2bf_kernel(
    const float* __restrict__ in, unsigned short* __restrict__ o)
{
    const size_t i = ((size_t)blockIdx.x * 256 + threadIdx.x) * 8;
    const float4 a = *(const float4*)(in + i);
    const float4 b = *(const float4*)(in + i + 4);
    ushort4 p0, p1;
    p0.x = f2bf(a.x); p0.y = f2bf(a.y); p0.z = f2bf(a.z); p0.w = f2bf(a.w);
    p1.x = f2bf(b.x); p1.y = f2bf(b.y); p1.z = f2bf(b.z); p1.w = f2bf(b.w);
    *(ushort4*)(o + i) = p0;
    *(ushort4*)(o + i + 4) = p1;
}

// ---------------------------------------------------------------------------
// GEMM: C[Mrows,N] = A[Mrows,K] @ Bt[N,K]^T + epilogue
// 128x128 tile, BK=64, 4 waves, mfma_f32_16x16x32_bf16.
// global_load_lds (16B) into LINEAR LDS; content XOR-swizzled via pre-swizzled
// global source (rule 21). EPI: 0 bias, 1 bias+res, 2 bias+ELU.
// (Exact R6 structure - proven 659 us config.)
// ---------------------------------------------------------------------------
template<int EPI, bool AF32, bool OBF, bool RBF>
__global__ __launch_bounds__(256, 4) void gemm_kernel(
    const void* __restrict__ Ap,
    const unsigned short* __restrict__ Bt,
    const float* __restrict__ bias,
    const void* __restrict__ resp,
    void* __restrict__ Cp,
    int N, int K)
{
    __shared__ __align__(16) char AsRaw[AF32 ? 32768 : 16384];
    __shared__ __align__(16) char BsRaw[16384];

    const int t = threadIdx.x;
    const int lane = t & 63;
    const int wv = t >> 6;
    const int wr = wv >> 1, wc = wv & 1;
    const int row0 = blockIdx.y * 128;
    const int col0 = blockIdx.x * 128;
    const int l15 = lane & 15, l4 = lane >> 4;

    const int bRow = t >> 3;
    const int bGran = (t & 7) ^ ((t >> 3) & 7);
    const int aRowF = t >> 4;
    const int aGranF = (t & 15) ^ ((t >> 4) & 15);

    f32x4 acc[4][4] = {};

    for (int k0 = 0; k0 < K; k0 += 64) {
#pragma unroll
        for (int r = 0; r < 4; ++r) {
            const int row = r * 32 + bRow;
            gl16(Bt + (size_t)(col0 + row) * K + k0 + bGran * 8,
                 (void*)(BsRaw + r * 4096 + t * 16));
        }
        if (AF32) {
            const float* A = (const float*)Ap;
#pragma unroll
            for (int r = 0; r < 8; ++r) {
                const int row = r * 16 + aRowF;
                gl16(A + (size_t)(row0 + row) * K + k0 + aGranF * 4,
                     (void*)(AsRaw + r * 4096 + t * 16));
            }
        } else {
            const unsigned short* A = (const unsigned short*)Ap;
#pragma unroll
            for (int r = 0; r < 4; ++r) {
                const int row = r * 32 + bRow;
                gl16(A + (size_t)(row0 + row) * K + k0 + bGran * 8,
                     (void*)(AsRaw + r * 4096 + t * 16));
            }
        }
        __syncthreads();

#pragma unroll
        for (int ks = 0; ks < 2; ++ks) {
            bf16x8 af[4], bfv[4];
            if (AF32) {
#pragma unroll
                for (int mi = 0; mi < 4; ++mi) {
                    const int row = wr * 64 + mi * 16 + l15;
                    const int sw = (row & 15) << 4;
                    const float4 x0 = *(const float4*)(AsRaw + row * 256 + ((ks * 128 + l4 * 32) ^ sw));
                    const float4 x1 = *(const float4*)(AsRaw + row * 256 + ((ks * 128 + l4 * 32 + 16) ^ sw));
                    bf16x8 v;
                    v[0] = (__bf16)x0.x; v[1] = (__bf16)x0.y;
                    v[2] = (__bf16)x0.z; v[3] = (__bf16)x0.w;
                    v[4] = (__bf16)x1.x; v[5] = (__bf16)x1.y;
                    v[6] = (__bf16)x1.z; v[7] = (__bf16)x1.w;
                    af[mi] = v;
                }
            } else {
#pragma unroll
                for (int mi = 0; mi < 4; ++mi) {
                    const int row = wr * 64 + mi * 16 + l15;
                    af[mi] = *(const bf16x8*)(AsRaw + row * 128 + ((ks * 64 + l4 * 16) ^ ((row & 7) << 4)));
                }
            }
#pragma unroll
            for (int ni = 0; ni < 4; ++ni) {
                const int row = wc * 64 + ni * 16 + l15;
                bfv[ni] = *(const bf16x8*)(BsRaw + row * 128 + ((ks * 64 + l4 * 16) ^ ((row & 7) << 4)));
            }
#pragma unroll
            for (int mi = 0; mi < 4; ++mi)
#pragma unroll
                for (int ni = 0; ni < 4; ++ni)
                    acc[mi][ni] = __builtin_amdgcn_mfma_f32_16x16x32_bf16(
                        af[mi], bfv[ni], acc[mi][ni], 0, 0, 0);
        }
        __syncthreads();
    }

#pragma unroll
    for (int ni = 0; ni < 4; ++ni) {
        const int col = col0 + wc * 64 + ni * 16 + l15;
        const float bc = bias[col];
#pragma unroll
        for (int mi = 0; mi < 4; ++mi) {
#pragma unroll
            for (int r = 0; r < 4; ++r) {
                const int row = row0 + wr * 64 + mi * 16 + l4 * 4 + r;
                float v = acc[mi][ni][r] + bc;
                if (EPI == 1) {
                    if (RBF) v += bf2f(((const unsigned short*)resp)[(size_t)row * N + col]);
                    else     v += ((const float*)resp)[(size_t)row * N + col];
                }
                if (EPI == 2) v = v > 0.f ? v : expm1f(v);
                if (OBF) ((unsigned short*)Cp)[(size_t)row * N + col] = f2bf(v);
                else     ((float*)Cp)[(size_t)row * N + col] = v;
            }
        }
    }
}

// ---------------------------------------------------------------------------
// Fused QKV GEMM (R6 proven) + XCD-chunked swizzle (R11's single change):
// nwg = 24*128 = 3072 (%8==0, bijective). Each XCD gets a contiguous chunk
// of 384 blocks = 16 row-panels x 24 col-blocks -> A row-panels fetched
// ~once per XCD L2 instead of scattered across 8 XCDs.
// ---------------------------------------------------------------------------
__global__ __launch_bounds__(256, 4) void qkv_gemm_kernel(
    const unsigned short* __restrict__ A,     // xbf [BS_, 1024]
    const unsigned short* __restrict__ Bt,    // Wqkvt [3072][1024]
    const float* __restrict__ bq, const float* __restrict__ bk,
    const float* __restrict__ bv,
    unsigned short* __restrict__ outQ, unsigned short* __restrict__ outK,
    unsigned short* __restrict__ outV)
{
    const int K = 1024;
    __shared__ __align__(16) char AsRaw[16384];
    __shared__ __align__(16) char BsRaw[16384];

    const int t = threadIdx.x;
    const int lane = t & 63;
    const int wv = t >> 6;
    const int wr = wv >> 1, wc = wv & 1;
    // XCD-chunked bijective swizzle (nwg = 3072, multiple of 8)
    const int nwg = gridDim.x * gridDim.y;
    int bid = blockIdx.y * gridDim.x + blockIdx.x;
    bid = (bid & 7) * (nwg >> 3) + (bid >> 3);
    const int row0 = (bid / gridDim.x) * 128;
    const int col0 = (bid % gridDim.x) * 128;
    const int l15 = lane & 15, l4 = lane >> 4;

    const int bRow = t >> 3;
    const int bGran = (t & 7) ^ ((t >> 3) & 7);

    f32x4 acc[4][4] = {};

    for (int k0 = 0; k0 < K; k0 += 64) {
#pragma unroll
        for (int r = 0; r < 4; ++r) {
            const int row = r * 32 + bRow;
            gl16(Bt + (size_t)(col0 + row) * K + k0 + bGran * 8,
                 (void*)(BsRaw + r * 4096 + t * 16));
        }
#pragma unroll
        for (int r = 0; r < 4; ++r) {
            const int row = r * 32 + bRow;
            gl16(A + (size_t)(row0 + row) * K + k0 + bGran * 8,
                 (void*)(AsRaw + r * 4096 + t * 16));
        }
        __syncthreads();

#pragma unroll
        for (int ks = 0; ks < 2; ++ks) {
            bf16x8 af[4], bfv[4];
#pragma unroll
            for (int mi = 0; mi < 4; ++mi) {
                const int row = wr * 64 + mi * 16 + l15;
                af[mi] = *(const bf16x8*)(AsRaw + row * 128 + ((ks * 64 + l4 * 16) ^ ((row & 7) << 4)));
            }
#pragma unroll
            for (int ni = 0; ni < 4; ++ni) {
                const int row = wc * 64 + ni * 16 + l15;
                bfv[ni] = *(const bf16x8*)(BsRaw + row * 128 + ((ks * 64 + l4 * 16) ^ ((row & 7) << 4)));
            }
#pragma unroll
            for (int mi = 0; mi < 4; ++mi)
#pragma unroll
                for (int ni = 0; ni < 4; ++ni)
                    acc[mi][ni] = __builtin_amdgcn_mfma_f32_16x16x32_bf16(
                        af[mi], bfv[ni], acc[mi][ni], 0, 0, 0);
        }
        __syncthreads();
    }

#pragma unroll
    for (int ni = 0; ni < 4; ++ni) {
        const int colg = col0 + wc * 64 + ni * 16 + l15;   // 0..3071
        const int sel = colg >> 10;
        const int colr = colg & 1023;
        const float* bp = (sel == 0) ? bq : (sel == 1) ? bk : bv;
        unsigned short* op = (sel == 0) ? outQ : (sel == 1) ? outK : outV;
        const float bc = bp[colr];
#pragma unroll
        for (int mi = 0; mi < 4; ++mi) {
#pragma unroll
            for (int r = 0; r < 4; ++r) {
                const int row = row0 + wr * 64 + mi * 16 + l4 * 4 + r;
                op[(size_t)row * D_ + colr] = f2bf(acc[mi][ni][r] + bc);
            }
        }
    }
}

// ---------------------------------------------------------------------------
// kv kernel (MFMA): per (bh, chunk of 512 rows), 8 sub-tiles of 64 rows.
// ---------------------------------------------------------------------------
__global__ __launch_bounds__(256) void kv_mfma_kernel(
    const unsigned short* __restrict__ Kmat,
    const unsigned short* __restrict__ Vmat,
    const float* __restrict__ omega,
    float* __restrict__ kvp)
{
    __shared__ unsigned short omegaB[128][72];
    __shared__ union U2 {
        unsigned short kA[64][72];
        unsigned short vT[80 * 64];
    } u2;
    __shared__ unsigned short pk[64][130];
    __shared__ float sqp[256];
    __shared__ float sqk[64];

    const int bh = blockIdx.x, chunk = blockIdx.y;
    const int b = bh >> 4, h = bh & 15;
    const int t = threadIdx.x, l = t & 63, w = t >> 6;
    const int l15 = l & 15, l4 = l >> 4;
    const int srow0 = b * S_ + chunk * 512;

    {
        const int m = t >> 1, d0 = (t & 1) * 32;
        const float* src = omega + m * 64 + d0;
#pragma unroll
        for (int i = 0; i < 8; ++i) {
            float4 v4 = *(const float4*)(src + i * 4);
            ushort4 p;
            p.x = f2bf(v4.x * QSCALE); p.y = f2bf(v4.y * QSCALE);
            p.z = f2bf(v4.z * QSCALE); p.w = f2bf(v4.w * QSCALE);
            *(ushort4*)&omegaB[m][d0 + i * 4] = p;
        }
    }

    f32x4 akv[5][2] = {};

    for (int sub = 0; sub < 8; ++sub) {
        {
            const int r = t >> 2, d0 = (t & 3) * 16;
            const unsigned short* src = Kmat + (size_t)(srow0 + sub * 64 + r) * D_ + h * 64 + d0;
            uint4 v0 = *(const uint4*)src;
            uint4 v1 = *(const uint4*)(src + 8);
            *(uint4*)&u2.kA[r][d0] = v0;
            *(uint4*)&u2.kA[r][d0 + 8] = v1;
            float a = 0.f;
            const unsigned short* pv = (const unsigned short*)&v0;
#pragma unroll
            for (int j = 0; j < 8; ++j) { float f = bf2f(pv[j]); a += f * f; }
            pv = (const unsigned short*)&v1;
#pragma unroll
            for (int j = 0; j < 8; ++j) { float f = bf2f(pv[j]); a += f * f; }
            sqp[t] = a;
        }
        __syncthreads();
        if (t < 64)
            sqk[t] = (sqp[4 * t] + sqp[4 * t + 1] + sqp[4 * t + 2] + sqp[4 * t + 3]) * (QSCALE2 * 0.5f);
        f32x4 a1[8] = {};
#pragma unroll
        for (int ks = 0; ks < 2; ++ks) {
            bf16x8 af = *(const bf16x8*)&u2.kA[w * 16 + l15][ks * 32 + l4 * 8];
            bf16x8 bf[8];
#pragma unroll
            for (int ni = 0; ni < 8; ++ni)
                bf[ni] = *(const bf16x8*)&omegaB[ni * 16 + l15][ks * 32 + l4 * 8];
#pragma unroll
            for (int ni = 0; ni < 8; ++ni)
                a1[ni] = __builtin_amdgcn_mfma_f32_16x16x32_bf16(af, bf[ni], a1[ni], 0, 0, 0);
        }
        __syncthreads();
#pragma unroll
        for (int ni = 0; ni < 8; ++ni)
#pragma unroll
            for (int r = 0; r < 4; ++r) {
                int row = w * 16 + l4 * 4 + r;
                float p = expf(a1[ni][r] - sqk[row]) * INVSQRTM + 1e-6f;
                pk[row][ni * 16 + l15] = f2bf(p);
            }
        {
            const int s = t >> 2, d0 = (t & 3) * 16;
            const unsigned short* src = Vmat + (size_t)(srow0 + sub * 64 + s) * D_ + h * 64 + d0;
            uint4 v0 = *(const uint4*)src;
            uint4 v1 = *(const uint4*)(src + 8);
            unsigned short tmp[16];
            *(uint4*)&tmp[0] = v0; *(uint4*)&tmp[8] = v1;
            char* vb = (char*)u2.vT;
#pragma unroll
            for (int j = 0; j < 16; ++j) {
                int d = d0 + j;
                int byte = (d * 128 + s * 2) ^ ((d & 7) << 4);
                *(unsigned short*)(vb + byte) = tmp[j];
            }
        }
        if (t < 128) {
            int row = 64 + (t >> 3), s0 = (t & 7) * 8;
            unsigned short val = (row == 64) ? (unsigned short)0x3F80 : (unsigned short)0;
            char* vb = (char*)u2.vT;
#pragma unroll
            for (int j = 0; j < 8; ++j) {
                int byte = (row * 128 + (s0 + j) * 2) ^ ((row & 7) << 4);
                *(unsigned short*)(vb + byte) = val;
            }
        }
        __syncthreads();
#pragma unroll
        for (int ks = 0; ks < 2; ++ks) {
            bf16x8 af[5];
            const char* vb = (const char*)u2.vT;
#pragma unroll
            for (int at = 0; at < 5; ++at) {
                int d = at * 16 + l15;
                int byte = (d * 128 + (ks * 32 + l4 * 8) * 2) ^ ((d & 7) << 4);
                af[at] = *(const bf16x8*)(vb + byte);
            }
            bf16x8 bfr[2];
#pragma unroll
            for (int nt = 0; nt < 2; ++nt) {
                unsigned short tmp[8];
#pragma unroll
                for (int j = 0; j < 8; ++j)
                    tmp[j] = pk[ks * 32 + l4 * 8 + j][w * 32 + nt * 16 + l15];
                bfr[nt] = *(const bf16x8*)tmp;
            }
#pragma unroll
            for (int at = 0; at < 5; ++at)
#pragma unroll
                for (int nt = 0; nt < 2; ++nt)
                    akv[at][nt] = __builtin_amdgcn_mfma_f32_16x16x32_bf16(af[at], bfr[nt], akv[at][nt], 0, 0, 0);
        }
        __syncthreads();
    }

    const size_t base = ((size_t)chunk * 64 + bh) * (80 * 128);
#pragma unroll
    for (int at = 0; at < 5; ++at)
#pragma unroll
        for (int nt = 0; nt < 2; ++nt)
#pragma unroll
            for (int r = 0; r < 4; ++r) {
                int row = at * 16 + l4 * 4 + r;
                int col = w * 32 + nt * 16 + l15;
                kvp[base + (size_t)row * 128 + col] = akv[at][nt][r];
            }
}

__global__ __launch_bounds__(256) void kvt_reduce_kernel(
    const float* __restrict__ kvp, unsigned short* __restrict__ kvT)
{
    const int idx = blockIdx.x * 256 + threadIdx.x;
    const int NKV = 64 * 80 * 128;
    float s = 0.f;
#pragma unroll
    for (int c = 0; c < 8; ++c) s += kvp[(size_t)c * NKV + idx];
    kvT[idx] = f2bf(s);
}

// ---------------------------------------------------------------------------
// attn kernel (MFMA): per (bh, 128-row tile).
// ---------------------------------------------------------------------------
__global__ __launch_bounds__(256) void attn_mfma_kernel(
    const unsigned short* __restrict__ Qmat,
    const float* __restrict__ omega,
    const unsigned short* __restrict__ kvT,
    unsigned short* __restrict__ attn)
{
    __shared__ union U {
        struct { unsigned short omegaB[128][72]; unsigned short qA[128][72]; } s1;
        struct { unsigned short pq[128][136]; } s2;
    } u;
    __shared__ unsigned short kvB[80][136];
    __shared__ float sqp[256];
    __shared__ float sqr[128];
    __shared__ float zden[128];

    const int bh = blockIdx.x, sc = blockIdx.y;
    const int b = bh >> 4, h = bh & 15;
    const int t = threadIdx.x, l = t & 63, w = t >> 6;
    const int l15 = l & 15, l4 = l >> 4;
    const int srow0 = b * S_ + sc * 128;

    {
        const int m = t >> 1, d0 = (t & 1) * 32;
        const float* src = omega + m * 64 + d0;
#pragma unroll
        for (int i = 0; i < 8; ++i) {
            float4 v4 = *(const float4*)(src + i * 4);
            ushort4 p;
            p.x = f2bf(v4.x * QSCALE); p.y = f2bf(v4.y * QSCALE);
            p.z = f2bf(v4.z * QSCALE); p.w = f2bf(v4.w * QSCALE);
            *(ushort4*)&u.s1.omegaB[m][d0 + i * 4] = p;
        }
    }
    if (t < 160) {
        const int rr = t >> 1, c0 = (t & 1) * 64;
        const uint4* src = (const uint4*)(kvT + ((size_t)bh * 80 + rr) * 128 + c0);
#pragma unroll
        for (int i = 0; i < 8; ++i)
            *(uint4*)&kvB[rr][c0 + i * 8] = src[i];
    }
    {
        const int r = t >> 1, d0 = (t & 1) * 32;
        const unsigned short* src = Qmat + (size_t)(srow0 + r) * D_ + h * 64 + d0;
        float a = 0.f;
#pragma unroll
        for (int i = 0; i < 4; ++i) {
            uint4 v8 = *(const uint4*)(src + i * 8);
            *(uint4*)&u.s1.qA[r][d0 + i * 8] = v8;
            const unsigned short* pv = (const unsigned short*)&v8;
#pragma unroll
            for (int j = 0; j < 8; ++j) { float f = bf2f(pv[j]); a += f * f; }
        }
        sqp[t] = a;
    }
    __syncthreads();
    if (t < 128) sqr[t] = (sqp[2 * t] + sqp[2 * t + 1]) * (QSCALE2 * 0.5f);

    f32x4 acc1[2][8] = {};
#pragma unroll
    for (int ks = 0; ks < 2; ++ks) {
        bf16x8 af[2], bf[8];
#pragma unroll
        for (int mi = 0; mi < 2; ++mi)
            af[mi] = *(const bf16x8*)&u.s1.qA[w * 32 + mi * 16 + l15][ks * 32 + l4 * 8];
#pragma unroll
        for (int ni = 0; ni < 8; ++ni)
            bf[ni] = *(const bf16x8*)&u.s1.omegaB[ni * 16 + l15][ks * 32 + l4 * 8];
#pragma unroll
        for (int mi = 0; mi < 2; ++mi)
#pragma unroll
            for (int ni = 0; ni < 8; ++ni)
                acc1[mi][ni] = __builtin_amdgcn_mfma_f32_16x16x32_bf16(af[mi], bf[ni], acc1[mi][ni], 0, 0, 0);
    }
    __syncthreads();

#pragma unroll
    for (int mi = 0; mi < 2; ++mi)
#pragma unroll
        for (int ni = 0; ni < 8; ++ni)
#pragma unroll
            for (int r = 0; r < 4; ++r) {
                int row = w * 32 + mi * 16 + l4 * 4 + r;
                float p = expf(acc1[mi][ni][r] - sqr[row]) * INVSQRTM + 1e-6f;
                u.s2.pq[row][ni * 16 + l15] = f2bf(p);
            }
    __syncthreads();

    f32x4 acc2[2][5] = {};
#pragma unroll
    for (int ks = 0; ks < 4; ++ks) {
        bf16x8 af[2], bf[5];
#pragma unroll
        for (int mi = 0; mi < 2; ++mi)
            af[mi] = *(const bf16x8*)&u.s2.pq[w * 32 + mi * 16 + l15][ks * 32 + l4 * 8];
#pragma unroll
        for (int ni = 0; ni < 5; ++ni)
            bf[ni] = *(const bf16x8*)&kvB[ni * 16 + l15][ks * 32 + l4 * 8];
#pragma unroll
        for (int mi = 0; mi < 2; ++mi)
#pragma unroll
            for (int ni = 0; ni < 5; ++ni)
                acc2[mi][ni] = __builtin_amdgcn_mfma_f32_16x16x32_bf16(af[mi], bf[ni], acc2[mi][ni], 0, 0, 0);
    }
    if (l15 == 0) {
#pragma unroll
        for (int mi = 0; mi < 2; ++mi)
#pragma unroll
            for (int r = 0; r < 4; ++r) {
                int row = w * 32 + mi * 16 + l4 * 4 + r;
                zden[row] = 1.f / (acc2[mi][4][r] + 1e-6f);
            }
    }
    __syncthreads();
#pragma unroll
    for (int ni = 0; ni < 4; ++ni)
#pragma unroll
        for (int mi = 0; mi < 2; ++mi)
#pragma unroll
            for (int r = 0; r < 4; ++r) {
                int row = w * 32 + mi * 16 + l4 * 4 + r;
                float o = acc2[mi][ni][r] * zden[row];
                attn[(size_t)(srow0 + row) * D_ + h * 64 + ni * 16 + l15] = f2bf(o);
            }
}

// ---------------------------------------------------------------------------
// LayerNorm over D_=1024, one row per block.
// ---------------------------------------------------------------------------
template<bool INBF, bool OUTBF>
__global__ __launch_bounds__(256) void layernorm_kernel(
    const void* __restrict__ inp, const float* __restrict__ g,
    const float* __restrict__ be, void* __restrict__ outp)
{
    const int row = blockIdx.x;
    const int t = threadIdx.x;
    const int l = t & 63, w = t >> 6;
    float4 v;
    if (INBF) {
        const ushort4 r4 = *(const ushort4*)((const unsigned short*)inp + (size_t)row * D_ + t * 4);
        v.x = bf2f(r4.x); v.y = bf2f(r4.y); v.z = bf2f(r4.z); v.w = bf2f(r4.w);
    } else {
        v = *(const float4*)((const float*)inp + (size_t)row * D_ + t * 4);
    }
    float s = v.x + v.y + v.z + v.w;
    float ss = v.x * v.x + v.y * v.y + v.z * v.z + v.w * v.w;
#pragma unroll
    for (int o = 32; o > 0; o >>= 1) { s += __shfl_xor(s, o); ss += __shfl_xor(ss, o); }
    __shared__ float red[8];
    if (l == 0) { red[w] = s; red[4 + w] = ss; }
    __syncthreads();
    s = red[0] + red[1] + red[2] + red[3];
    ss = red[4] + red[5] + red[6] + red[7];
    const float mu = s * (1.f / D_);
    const float var = ss * (1.f / D_) - mu * mu;
    const float r = rsqrtf(var + 1e-6f);
    const float4 gg = *(const float4*)(g + t * 4);
    const float4 bb = *(const float4*)(be + t * 4);
    float4 o4;
    o4.x = (v.x - mu) * r * gg.x + bb.x;
    o4.y = (v.y - mu) * r * gg.y + bb.y;
    o4.z = (v.z - mu) * r * gg.z + bb.z;
    o4.w = (v.w - mu) * r * gg.w + bb.w;
    if (OUTBF) {
        ushort4 p;
        p.x = f2bf(o4.x); p.y = f2bf(o4.y); p.z = f2bf(o4.z); p.w = f2bf(o4.w);
        *(ushort4*)((unsigned short*)outp + (size_t)row * D_ + t * 4) = p;
    } else {
        *(float4*)((float*)outp + (size_t)row * D_ + t * 4) = o4;
    }
}

// ---------------------------------------------------------------------------
extern "C" void kernel_launch(void* const* d_in, const int* in_sizes, int n_in,
                              void* d_out, int out_size, void* d_ws, size_t ws_size,
                              hipStream_t stream)
{
    (void)in_sizes; (void)n_in; (void)out_size;
    const float* x     = (const float*)d_in[0];
    const float* Wq    = (const float*)d_in[1];
    const float* bq    = (const float*)d_in[2];
    const float* Wk    = (const float*)d_in[3];
    const float* bk    = (const float*)d_in[4];
    const float* Wv    = (const float*)d_in[5];
    const float* bv    = (const float*)d_in[6];
    const float* Wo    = (const float*)d_in[7];
    const float* bo    = (const float*)d_in[8];
    const float* omega = (const float*)d_in[9];
    const float* W1    = (const float*)d_in[10];
    const float* b1    = (const float*)d_in[11];
    const float* W2    = (const float*)d_in[12];
    const float* b2    = (const float*)d_in[13];
    const float* g1    = (const float*)d_in[14];
    const float* be1   = (const float*)d_in[15];
    const float* g2    = (const float*)d_in[16];
    const float* be2   = (const float*)d_in[17];
    float* out = (float*)d_out;

    const size_t ACT = (size_t)BS_ * D_;
    unsigned short* slotQ = (unsigned short*)d_ws;
    unsigned short* slotK = slotQ + ACT;
    unsigned short* slotV = slotK + ACT;
    float* kvp = (float*)(slotV + ACT);
    unsigned short* kvT = (unsigned short*)(kvp + (size_t)8 * 64 * 80 * 128);
    unsigned short* Wqkvt = kvT + (size_t)64 * 80 * 128;
    unsigned short* Wot = Wqkvt + (size_t)3 * D_ * D_;
    unsigned short* W1t = Wot + (size_t)D_ * D_;
    unsigned short* W2t = W1t + (size_t)D_ * DFF_;
    unsigned short* wsEnd = W2t + (size_t)DFF_ * D_;

    const size_t fixedBytes = (size_t)((char*)wsEnd - (char*)d_ws);
    char* cur = (char*)wsEnd;

    const bool useFused = ws_size >= fixedBytes + ACT * 2;
    unsigned short* xbf = nullptr;
    if (useFused) { xbf = (unsigned short*)cur; cur += ACT * 2; }
    const size_t usedBytes = (size_t)(cur - (char*)d_ws);

    int nch;
    unsigned short* ffn1;
    if (ws_size >= usedBytes + (size_t)BS_ * DFF_ * 2) {
        nch = 1;  ffn1 = (unsigned short*)cur;
    } else if (ws_size >= usedBytes + (size_t)(BS_ / 2) * DFF_ * 2) {
        nch = 2;  ffn1 = (unsigned short*)cur;
    } else {
        nch = 4;  ffn1 = slotK;
    }

    unsigned short* attn = slotK;
    unsigned short* tmp1 = slotV;
    unsigned short* out1 = slotQ;
    unsigned short* tmp2 = slotV;

    // 1. weights -> bf16 transposed (Wq/Wk/Wv concatenated along n)
    wconv_kernel<<<dim3(D_ / 32, D_ / 32), 256, 0, stream>>>(Wq, Wqkvt, D_, D_);
    wconv_kernel<<<dim3(D_ / 32, D_ / 32), 256, 0, stream>>>(Wk, Wqkvt + (size_t)D_ * D_, D_, D_);
    wconv_kernel<<<dim3(D_ / 32, D_ / 32), 256, 0, stream>>>(Wv, Wqkvt + (size_t)2 * D_ * D_, D_, D_);
    wconv_kernel<<<dim3(D_ / 32, D_ / 32), 256, 0, stream>>>(Wo, Wot, D_, D_);
    wconv_kernel<<<dim3(DFF_ / 32, D_ / 32), 256, 0, stream>>>(W1, W1t, D_, DFF_);
    wconv_kernel<<<dim3(D_ / 32, DFF_ / 32), 256, 0, stream>>>(W2, W2t, DFF_, D_);

    // 2. Q,K,V projections (fused 128^2, + XCD swizzle this round)
    if (useFused) {
        x2bf_kernel<<<dim3(BS_ * D_ / 2048), 256, 0, stream>>>(x, xbf);
        qkv_gemm_kernel<<<dim3(3 * D_ / 128, BS_ / 128), 256, 0, stream>>>(
            xbf, Wqkvt, bq, bk, bv, slotQ, slotK, slotV);
    } else {
        gemm_kernel<0, true, true, false><<<dim3(D_ / 128, BS_ / 128), 256, 0, stream>>>(x, Wqkvt, bq, nullptr, slotQ, D_, D_);
        gemm_kernel<0, true, true, false><<<dim3(D_ / 128, BS_ / 128), 256, 0, stream>>>(x, Wqkvt + (size_t)D_ * D_, bk, nullptr, slotK, D_, D_);
        gemm_kernel<0, true, true, false><<<dim3(D_ / 128, BS_ / 128), 256, 0, stream>>>(x, Wqkvt + (size_t)2 * D_ * D_, bv, nullptr, slotV, D_, D_);
    }

    // 3. phi(k) -> kvT_aug partials -> reduce to bf16
    kv_mfma_kernel<<<dim3(64, 8), 256, 0, stream>>>(slotK, slotV, omega, kvp);
    kvt_reduce_kernel<<<dim3(2560), 256, 0, stream>>>(kvp, kvT);

    // 4. phi(q) -> normalized attention (bf16, overwrites k slot)
    attn_mfma_kernel<<<dim3(64, 32), 256, 0, stream>>>(slotQ, omega, kvT, attn);

    // 5. Wo projection + residual(x f32) -> tmp1; LN -> out1
    gemm_kernel<1, false, true, false><<<dim3(D_ / 128, BS_ / 128), 256, 0, stream>>>(attn, Wot, bo, x, tmp1, D_, D_);
    layernorm_kernel<true, true><<<dim3(BS_), 256, 0, stream>>>(tmp1, g1, be1, out1);

    // 6. FFN in nch row-chunks: elu(out1@W1+b1) @W2+b2+out1
    const int rows = BS_ / nch;
    for (int c = 0; c < nch; ++c) {
        const size_t off = (size_t)c * rows * D_;
        gemm_kernel<2, false, true, false><<<dim3(DFF_ / 128, rows / 128), 256, 0, stream>>>(
            out1 + off, W1t, b1, nullptr, ffn1, DFF_, D_);
        gemm_kernel<1, false, true, true><<<dim3(D_ / 128, rows / 128), 256, 0, stream>>>(
            ffn1, W2t, b2, out1 + off, tmp2 + off, D_, DFF_);
    }

    // 7. LN2 -> out (f32)
    layernorm_kernel<true, false><<<dim3(BS_), 256, 0, stream>>>(tmp2, g2, be2, out);
}

// Round 12
// 662.212 us; speedup vs baseline: 1.2796x; 1.0089x over previous
//
#include <hip/hip_runtime.h>
#include <hip/hip_bf16.h>
#include <math.h>

#define B_   4
#define S_   4096
#define D_   1024
#define H_   16
#define M_   128
#define DH_  64
#define DFF_ 4096
#define BS_  (B_*S_)   // 16384 rows

typedef float  f32x4  __attribute__((ext_vector_type(4)));
typedef __bf16 bf16x8 __attribute__((ext_vector_type(8)));

__device__ __forceinline__ unsigned short f2bf(float f) {
    unsigned int u = __float_as_uint(f);
    u += 0x7FFFu + ((u >> 16) & 1u);     // round-to-nearest-even
    return (unsigned short)(u >> 16);
}
__device__ __forceinline__ float bf2f(unsigned short u) {
    return __uint_as_float((unsigned int)u << 16);
}

typedef __attribute__((address_space(1))) void void_g;
typedef __attribute__((address_space(3))) void void_l;
__device__ __forceinline__ void gl16(const void* g, void* l) {
    __builtin_amdgcn_global_load_lds((const void_g*)g, (void_l*)l, 16, 0, 0);
}

#define QSCALE    0.35355339059327373f   // DH^-0.25
#define QSCALE2   0.125f                 // DH^-0.5
#define INVSQRTM  0.08838834764831845f   // 1/sqrt(128)

// ---------------------------------------------------------------------------
// Weight convert + transpose:  Wt[n][k] = bf16(W[k][n])
// ---------------------------------------------------------------------------
__global__ __launch_bounds__(256) void wconv_kernel(
    const float* __restrict__ W, unsigned short* __restrict__ Wt, int Kd, int Nd)
{
    __shared__ float ts[32][33];
    const int n0 = blockIdx.x * 32, k0 = blockIdx.y * 32;
    const int c = threadIdx.x & 31, rg = threadIdx.x >> 5;
#pragma unroll
    for (int i = 0; i < 4; ++i) {
        int r = rg * 4 + i;
        ts[r][c] = W[(size_t)(k0 + r) * Nd + n0 + c];
    }
    __syncthreads();
#pragma unroll
    for (int i = 0; i < 4; ++i) {
        int r = rg * 4 + i;
        Wt[(size_t)(n0 + r) * Kd + k0 + c] = f2bf(ts[c][r]);
    }
}

// x (f32) -> bf16, 8 elems/thread
__global__ __launch_bounds__(256) void x2bf_kernel(
    const float* __restrict__ in, unsigned short* __restrict__ o)
{
    const size_t i = ((size_t)blockIdx.x * 256 + threadIdx.x) * 8;
    const float4 a = *(const float4*)(in + i);
    const float4 b = *(const float4*)(in + i + 4);
    ushort4 p0, p1;
    p0.x = f2bf(a.x); p0.y = f2bf(a.y); p0.z = f2bf(a.z); p0.w = f2bf(a.w);
    p1.x = f2bf(b.x); p1.y = f2bf(b.y); p1.z = f2bf(b.z); p1.w = f2bf(b.w);
    *(ushort4*)(o + i) = p0;
    *(ushort4*)(o + i + 4) = p1;
}

// ---------------------------------------------------------------------------
// GEMM: C[Mrows,N] = A[Mrows,K] @ Bt[N,K]^T + epilogue
// 128x128 tile, BK=64, 4 waves, mfma_f32_16x16x32_bf16.
// global_load_lds (16B) into LINEAR LDS; content XOR-swizzled via pre-swizzled
// global source (rule 21). EPI: 0 bias, 1 bias+res, 2 bias+ELU.
// (Exact R6 structure - proven 659 us config.)
// ---------------------------------------------------------------------------
template<int EPI, bool AF32, bool OBF, bool RBF>
__global__ __launch_bounds__(256, 4) void gemm_kernel(
    const void* __restrict__ Ap,
    const unsigned short* __restrict__ Bt,
    const float* __restrict__ bias,
    const void* __restrict__ resp,
    void* __restrict__ Cp,
    int N, int K)
{
    __shared__ __align__(16) char AsRaw[AF32 ? 32768 : 16384];
    __shared__ __align__(16) char BsRaw[16384];

    const int t = threadIdx.x;
    const int lane = t & 63;
    const int wv = t >> 6;
    const int wr = wv >> 1, wc = wv & 1;
    const int row0 = blockIdx.y * 128;
    const int col0 = blockIdx.x * 128;
    const int l15 = lane & 15, l4 = lane >> 4;

    const int bRow = t >> 3;
    const int bGran = (t & 7) ^ ((t >> 3) & 7);
    const int aRowF = t >> 4;
    const int aGranF = (t & 15) ^ ((t >> 4) & 15);

    f32x4 acc[4][4] = {};

    for (int k0 = 0; k0 < K; k0 += 64) {
#pragma unroll
        for (int r = 0; r < 4; ++r) {
            const int row = r * 32 + bRow;
            gl16(Bt + (size_t)(col0 + row) * K + k0 + bGran * 8,
                 (void*)(BsRaw + r * 4096 + t * 16));
        }
        if (AF32) {
            const float* A = (const float*)Ap;
#pragma unroll
            for (int r = 0; r < 8; ++r) {
                const int row = r * 16 + aRowF;
                gl16(A + (size_t)(row0 + row) * K + k0 + aGranF * 4,
                     (void*)(AsRaw + r * 4096 + t * 16));
            }
        } else {
            const unsigned short* A = (const unsigned short*)Ap;
#pragma unroll
            for (int r = 0; r < 4; ++r) {
                const int row = r * 32 + bRow;
                gl16(A + (size_t)(row0 + row) * K + k0 + bGran * 8,
                     (void*)(AsRaw + r * 4096 + t * 16));
            }
        }
        __syncthreads();

#pragma unroll
        for (int ks = 0; ks < 2; ++ks) {
            bf16x8 af[4], bfv[4];
            if (AF32) {
#pragma unroll
                for (int mi = 0; mi < 4; ++mi) {
                    const int row = wr * 64 + mi * 16 + l15;
                    const int sw = (row & 15) << 4;
                    const float4 x0 = *(const float4*)(AsRaw + row * 256 + ((ks * 128 + l4 * 32) ^ sw));
                    const float4 x1 = *(const float4*)(AsRaw + row * 256 + ((ks * 128 + l4 * 32 + 16) ^ sw));
                    bf16x8 v;
                    v[0] = (__bf16)x0.x; v[1] = (__bf16)x0.y;
                    v[2] = (__bf16)x0.z; v[3] = (__bf16)x0.w;
                    v[4] = (__bf16)x1.x; v[5] = (__bf16)x1.y;
                    v[6] = (__bf16)x1.z; v[7] = (__bf16)x1.w;
                    af[mi] = v;
                }
            } else {
#pragma unroll
                for (int mi = 0; mi < 4; ++mi) {
                    const int row = wr * 64 + mi * 16 + l15;
                    af[mi] = *(const bf16x8*)(AsRaw + row * 128 + ((ks * 64 + l4 * 16) ^ ((row & 7) << 4)));
                }
            }
#pragma unroll
            for (int ni = 0; ni < 4; ++ni) {
                const int row = wc * 64 + ni * 16 + l15;
                bfv[ni] = *(const bf16x8*)(BsRaw + row * 128 + ((ks * 64 + l4 * 16) ^ ((row & 7) << 4)));
            }
#pragma unroll
            for (int mi = 0; mi < 4; ++mi)
#pragma unroll
                for (int ni = 0; ni < 4; ++ni)
                    acc[mi][ni] = __builtin_amdgcn_mfma_f32_16x16x32_bf16(
                        af[mi], bfv[ni], acc[mi][ni], 0, 0, 0);
        }
        __syncthreads();
    }

#pragma unroll
    for (int ni = 0; ni < 4; ++ni) {
        const int col = col0 + wc * 64 + ni * 16 + l15;
        const float bc = bias[col];
#pragma unroll
        for (int mi = 0; mi < 4; ++mi) {
#pragma unroll
            for (int r = 0; r < 4; ++r) {
                const int row = row0 + wr * 64 + mi * 16 + l4 * 4 + r;
                float v = acc[mi][ni][r] + bc;
                if (EPI == 1) {
                    if (RBF) v += bf2f(((const unsigned short*)resp)[(size_t)row * N + col]);
                    else     v += ((const float*)resp)[(size_t)row * N + col];
                }
                if (EPI == 2) v = v > 0.f ? v : expm1f(v);
                if (OBF) ((unsigned short*)Cp)[(size_t)row * N + col] = f2bf(v);
                else     ((float*)Cp)[(size_t)row * N + col] = v;
            }
        }
    }
}

// ---------------------------------------------------------------------------
// Fused QKV GEMM (exact R6 form, identity block mapping - proven 104 us).
// grid (24, 128).
// ---------------------------------------------------------------------------
__global__ __launch_bounds__(256, 4) void qkv_gemm_kernel(
    const unsigned short* __restrict__ A,     // xbf [BS_, 1024]
    const unsigned short* __restrict__ Bt,    // Wqkvt [3072][1024]
    const float* __restrict__ bq, const float* __restrict__ bk,
    const float* __restrict__ bv,
    unsigned short* __restrict__ outQ, unsigned short* __restrict__ outK,
    unsigned short* __restrict__ outV)
{
    const int K = 1024;
    __shared__ __align__(16) char AsRaw[16384];
    __shared__ __align__(16) char BsRaw[16384];

    const int t = threadIdx.x;
    const int lane = t & 63;
    const int wv = t >> 6;
    const int wr = wv >> 1, wc = wv & 1;
    const int row0 = blockIdx.y * 128;
    const int col0 = blockIdx.x * 128;
    const int l15 = lane & 15, l4 = lane >> 4;

    const int bRow = t >> 3;
    const int bGran = (t & 7) ^ ((t >> 3) & 7);

    f32x4 acc[4][4] = {};

    for (int k0 = 0; k0 < K; k0 += 64) {
#pragma unroll
        for (int r = 0; r < 4; ++r) {
            const int row = r * 32 + bRow;
            gl16(Bt + (size_t)(col0 + row) * K + k0 + bGran * 8,
                 (void*)(BsRaw + r * 4096 + t * 16));
        }
#pragma unroll
        for (int r = 0; r < 4; ++r) {
            const int row = r * 32 + bRow;
            gl16(A + (size_t)(row0 + row) * K + k0 + bGran * 8,
                 (void*)(AsRaw + r * 4096 + t * 16));
        }
        __syncthreads();

#pragma unroll
        for (int ks = 0; ks < 2; ++ks) {
            bf16x8 af[4], bfv[4];
#pragma unroll
            for (int mi = 0; mi < 4; ++mi) {
                const int row = wr * 64 + mi * 16 + l15;
                af[mi] = *(const bf16x8*)(AsRaw + row * 128 + ((ks * 64 + l4 * 16) ^ ((row & 7) << 4)));
            }
#pragma unroll
            for (int ni = 0; ni < 4; ++ni) {
                const int row = wc * 64 + ni * 16 + l15;
                bfv[ni] = *(const bf16x8*)(BsRaw + row * 128 + ((ks * 64 + l4 * 16) ^ ((row & 7) << 4)));
            }
#pragma unroll
            for (int mi = 0; mi < 4; ++mi)
#pragma unroll
                for (int ni = 0; ni < 4; ++ni)
                    acc[mi][ni] = __builtin_amdgcn_mfma_f32_16x16x32_bf16(
                        af[mi], bfv[ni], acc[mi][ni], 0, 0, 0);
        }
        __syncthreads();
    }

#pragma unroll
    for (int ni = 0; ni < 4; ++ni) {
        const int colg = col0 + wc * 64 + ni * 16 + l15;   // 0..3071
        const int sel = colg >> 10;
        const int colr = colg & 1023;
        const float* bp = (sel == 0) ? bq : (sel == 1) ? bk : bv;
        unsigned short* op = (sel == 0) ? outQ : (sel == 1) ? outK : outV;
        const float bc = bp[colr];
#pragma unroll
        for (int mi = 0; mi < 4; ++mi) {
#pragma unroll
            for (int r = 0; r < 4; ++r) {
                const int row = row0 + wr * 64 + mi * 16 + l4 * 4 + r;
                op[(size_t)row * D_ + colr] = f2bf(acc[mi][ni][r] + bc);
            }
        }
    }
}

// ---------------------------------------------------------------------------
// kv kernel (MFMA): per (bh, chunk of 512 rows), 8 sub-tiles of 64 rows.
// ---------------------------------------------------------------------------
__global__ __launch_bounds__(256) void kv_mfma_kernel(
    const unsigned short* __restrict__ Kmat,
    const unsigned short* __restrict__ Vmat,
    const float* __restrict__ omega,
    float* __restrict__ kvp)
{
    __shared__ unsigned short omegaB[128][72];
    __shared__ union U2 {
        unsigned short kA[64][72];
        unsigned short vT[80 * 64];
    } u2;
    __shared__ unsigned short pk[64][130];
    __shared__ float sqp[256];
    __shared__ float sqk[64];

    const int bh = blockIdx.x, chunk = blockIdx.y;
    const int b = bh >> 4, h = bh & 15;
    const int t = threadIdx.x, l = t & 63, w = t >> 6;
    const int l15 = l & 15, l4 = l >> 4;
    const int srow0 = b * S_ + chunk * 512;

    {
        const int m = t >> 1, d0 = (t & 1) * 32;
        const float* src = omega + m * 64 + d0;
#pragma unroll
        for (int i = 0; i < 8; ++i) {
            float4 v4 = *(const float4*)(src + i * 4);
            ushort4 p;
            p.x = f2bf(v4.x * QSCALE); p.y = f2bf(v4.y * QSCALE);
            p.z = f2bf(v4.z * QSCALE); p.w = f2bf(v4.w * QSCALE);
            *(ushort4*)&omegaB[m][d0 + i * 4] = p;
        }
    }

    f32x4 akv[5][2] = {};

    for (int sub = 0; sub < 8; ++sub) {
        {
            const int r = t >> 2, d0 = (t & 3) * 16;
            const unsigned short* src = Kmat + (size_t)(srow0 + sub * 64 + r) * D_ + h * 64 + d0;
            uint4 v0 = *(const uint4*)src;
            uint4 v1 = *(const uint4*)(src + 8);
            *(uint4*)&u2.kA[r][d0] = v0;
            *(uint4*)&u2.kA[r][d0 + 8] = v1;
            float a = 0.f;
            const unsigned short* pv = (const unsigned short*)&v0;
#pragma unroll
            for (int j = 0; j < 8; ++j) { float f = bf2f(pv[j]); a += f * f; }
            pv = (const unsigned short*)&v1;
#pragma unroll
            for (int j = 0; j < 8; ++j) { float f = bf2f(pv[j]); a += f * f; }
            sqp[t] = a;
        }
        __syncthreads();
        if (t < 64)
            sqk[t] = (sqp[4 * t] + sqp[4 * t + 1] + sqp[4 * t + 2] + sqp[4 * t + 3]) * (QSCALE2 * 0.5f);
        f32x4 a1[8] = {};
#pragma unroll
        for (int ks = 0; ks < 2; ++ks) {
            bf16x8 af = *(const bf16x8*)&u2.kA[w * 16 + l15][ks * 32 + l4 * 8];
            bf16x8 bf[8];
#pragma unroll
            for (int ni = 0; ni < 8; ++ni)
                bf[ni] = *(const bf16x8*)&omegaB[ni * 16 + l15][ks * 32 + l4 * 8];
#pragma unroll
            for (int ni = 0; ni < 8; ++ni)
                a1[ni] = __builtin_amdgcn_mfma_f32_16x16x32_bf16(af, bf[ni], a1[ni], 0, 0, 0);
        }
        __syncthreads();
#pragma unroll
        for (int ni = 0; ni < 8; ++ni)
#pragma unroll
            for (int r = 0; r < 4; ++r) {
                int row = w * 16 + l4 * 4 + r;
                float p = expf(a1[ni][r] - sqk[row]) * INVSQRTM + 1e-6f;
                pk[row][ni * 16 + l15] = f2bf(p);
            }
        {
            const int s = t >> 2, d0 = (t & 3) * 16;
            const unsigned short* src = Vmat + (size_t)(srow0 + sub * 64 + s) * D_ + h * 64 + d0;
            uint4 v0 = *(const uint4*)src;
            uint4 v1 = *(const uint4*)(src + 8);
            unsigned short tmp[16];
            *(uint4*)&tmp[0] = v0; *(uint4*)&tmp[8] = v1;
            char* vb = (char*)u2.vT;
#pragma unroll
            for (int j = 0; j < 16; ++j) {
                int d = d0 + j;
                int byte = (d * 128 + s * 2) ^ ((d & 7) << 4);
                *(unsigned short*)(vb + byte) = tmp[j];
            }
        }
        if (t < 128) {
            int row = 64 + (t >> 3), s0 = (t & 7) * 8;
            unsigned short val = (row == 64) ? (unsigned short)0x3F80 : (unsigned short)0;
            char* vb = (char*)u2.vT;
#pragma unroll
            for (int j = 0; j < 8; ++j) {
                int byte = (row * 128 + (s0 + j) * 2) ^ ((row & 7) << 4);
                *(unsigned short*)(vb + byte) = val;
            }
        }
        __syncthreads();
#pragma unroll
        for (int ks = 0; ks < 2; ++ks) {
            bf16x8 af[5];
            const char* vb = (const char*)u2.vT;
#pragma unroll
            for (int at = 0; at < 5; ++at) {
                int d = at * 16 + l15;
                int byte = (d * 128 + (ks * 32 + l4 * 8) * 2) ^ ((d & 7) << 4);
                af[at] = *(const bf16x8*)(vb + byte);
            }
            bf16x8 bfr[2];
#pragma unroll
            for (int nt = 0; nt < 2; ++nt) {
                unsigned short tmp[8];
#pragma unroll
                for (int j = 0; j < 8; ++j)
                    tmp[j] = pk[ks * 32 + l4 * 8 + j][w * 32 + nt * 16 + l15];
                bfr[nt] = *(const bf16x8*)tmp;
            }
#pragma unroll
            for (int at = 0; at < 5; ++at)
#pragma unroll
                for (int nt = 0; nt < 2; ++nt)
                    akv[at][nt] = __builtin_amdgcn_mfma_f32_16x16x32_bf16(af[at], bfr[nt], akv[at][nt], 0, 0, 0);
        }
        __syncthreads();
    }

    const size_t base = ((size_t)chunk * 64 + bh) * (80 * 128);
#pragma unroll
    for (int at = 0; at < 5; ++at)
#pragma unroll
        for (int nt = 0; nt < 2; ++nt)
#pragma unroll
            for (int r = 0; r < 4; ++r) {
                int row = at * 16 + l4 * 4 + r;
                int col = w * 32 + nt * 16 + l15;
                kvp[base + (size_t)row * 128 + col] = akv[at][nt][r];
            }
}

__global__ __launch_bounds__(256) void kvt_reduce_kernel(
    const float* __restrict__ kvp, unsigned short* __restrict__ kvT)
{
    const int idx = blockIdx.x * 256 + threadIdx.x;
    const int NKV = 64 * 80 * 128;
    float s = 0.f;
#pragma unroll
    for (int c = 0; c < 8; ++c) s += kvp[(size_t)c * NKV + idx];
    kvT[idx] = f2bf(s);
}

// ---------------------------------------------------------------------------
// attn kernel (MFMA): per (bh, 128-row tile).
// ---------------------------------------------------------------------------
__global__ __launch_bounds__(256) void attn_mfma_kernel(
    const unsigned short* __restrict__ Qmat,
    const float* __restrict__ omega,
    const unsigned short* __restrict__ kvT,
    unsigned short* __restrict__ attn)
{
    __shared__ union U {
        struct { unsigned short omegaB[128][72]; unsigned short qA[128][72]; } s1;
        struct { unsigned short pq[128][136]; } s2;
    } u;
    __shared__ unsigned short kvB[80][136];
    __shared__ float sqp[256];
    __shared__ float sqr[128];
    __shared__ float zden[128];

    const int bh = blockIdx.x, sc = blockIdx.y;
    const int b = bh >> 4, h = bh & 15;
    const int t = threadIdx.x, l = t & 63, w = t >> 6;
    const int l15 = l & 15, l4 = l >> 4;
    const int srow0 = b * S_ + sc * 128;

    {
        const int m = t >> 1, d0 = (t & 1) * 32;
        const float* src = omega + m * 64 + d0;
#pragma unroll
        for (int i = 0; i < 8; ++i) {
            float4 v4 = *(const float4*)(src + i * 4);
            ushort4 p;
            p.x = f2bf(v4.x * QSCALE); p.y = f2bf(v4.y * QSCALE);
            p.z = f2bf(v4.z * QSCALE); p.w = f2bf(v4.w * QSCALE);
            *(ushort4*)&u.s1.omegaB[m][d0 + i * 4] = p;
        }
    }
    if (t < 160) {
        const int rr = t >> 1, c0 = (t & 1) * 64;
        const uint4* src = (const uint4*)(kvT + ((size_t)bh * 80 + rr) * 128 + c0);
#pragma unroll
        for (int i = 0; i < 8; ++i)
            *(uint4*)&kvB[rr][c0 + i * 8] = src[i];
    }
    {
        const int r = t >> 1, d0 = (t & 1) * 32;
        const unsigned short* src = Qmat + (size_t)(srow0 + r) * D_ + h * 64 + d0;
        float a = 0.f;
#pragma unroll
        for (int i = 0; i < 4; ++i) {
            uint4 v8 = *(const uint4*)(src + i * 8);
            *(uint4*)&u.s1.qA[r][d0 + i * 8] = v8;
            const unsigned short* pv = (const unsigned short*)&v8;
#pragma unroll
            for (int j = 0; j < 8; ++j) { float f = bf2f(pv[j]); a += f * f; }
        }
        sqp[t] = a;
    }
    __syncthreads();
    if (t < 128) sqr[t] = (sqp[2 * t] + sqp[2 * t + 1]) * (QSCALE2 * 0.5f);

    f32x4 acc1[2][8] = {};
#pragma unroll
    for (int ks = 0; ks < 2; ++ks) {
        bf16x8 af[2], bf[8];
#pragma unroll
        for (int mi = 0; mi < 2; ++mi)
            af[mi] = *(const bf16x8*)&u.s1.qA[w * 32 + mi * 16 + l15][ks * 32 + l4 * 8];
#pragma unroll
        for (int ni = 0; ni < 8; ++ni)
            bf[ni] = *(const bf16x8*)&u.s1.omegaB[ni * 16 + l15][ks * 32 + l4 * 8];
#pragma unroll
        for (int mi = 0; mi < 2; ++mi)
#pragma unroll
            for (int ni = 0; ni < 8; ++ni)
                acc1[mi][ni] = __builtin_amdgcn_mfma_f32_16x16x32_bf16(af[mi], bf[ni], acc1[mi][ni], 0, 0, 0);
    }
    __syncthreads();

#pragma unroll
    for (int mi = 0; mi < 2; ++mi)
#pragma unroll
        for (int ni = 0; ni < 8; ++ni)
#pragma unroll
            for (int r = 0; r < 4; ++r) {
                int row = w * 32 + mi * 16 + l4 * 4 + r;
                float p = expf(acc1[mi][ni][r] - sqr[row]) * INVSQRTM + 1e-6f;
                u.s2.pq[row][ni * 16 + l15] = f2bf(p);
            }
    __syncthreads();

    f32x4 acc2[2][5] = {};
#pragma unroll
    for (int ks = 0; ks < 4; ++ks) {
        bf16x8 af[2], bf[5];
#pragma unroll
        for (int mi = 0; mi < 2; ++mi)
            af[mi] = *(const bf16x8*)&u.s2.pq[w * 32 + mi * 16 + l15][ks * 32 + l4 * 8];
#pragma unroll
        for (int ni = 0; ni < 5; ++ni)
            bf[ni] = *(const bf16x8*)&kvB[ni * 16 + l15][ks * 32 + l4 * 8];
#pragma unroll
        for (int mi = 0; mi < 2; ++mi)
#pragma unroll
            for (int ni = 0; ni < 5; ++ni)
                acc2[mi][ni] = __builtin_amdgcn_mfma_f32_16x16x32_bf16(af[mi], bf[ni], acc2[mi][ni], 0, 0, 0);
    }
    if (l15 == 0) {
#pragma unroll
        for (int mi = 0; mi < 2; ++mi)
#pragma unroll
            for (int r = 0; r < 4; ++r) {
                int row = w * 32 + mi * 16 + l4 * 4 + r;
                zden[row] = 1.f / (acc2[mi][4][r] + 1e-6f);
            }
    }
    __syncthreads();
#pragma unroll
    for (int ni = 0; ni < 4; ++ni)
#pragma unroll
        for (int mi = 0; mi < 2; ++mi)
#pragma unroll
            for (int r = 0; r < 4; ++r) {
                int row = w * 32 + mi * 16 + l4 * 4 + r;
                float o = acc2[mi][ni][r] * zden[row];
                attn[(size_t)(srow0 + row) * D_ + h * 64 + ni * 16 + l15] = f2bf(o);
            }
}

// ---------------------------------------------------------------------------
// LayerNorm over D_=1024, one row per block.
// ---------------------------------------------------------------------------
template<bool INBF, bool OUTBF>
__global__ __launch_bounds__(256) void layernorm_kernel(
    const void* __restrict__ inp, const float* __restrict__ g,
    const float* __restrict__ be, void* __restrict__ outp)
{
    const int row = blockIdx.x;
    const int t = threadIdx.x;
    const int l = t & 63, w = t >> 6;
    float4 v;
    if (INBF) {
        const ushort4 r4 = *(const ushort4*)((const unsigned short*)inp + (size_t)row * D_ + t * 4);
        v.x = bf2f(r4.x); v.y = bf2f(r4.y); v.z = bf2f(r4.z); v.w = bf2f(r4.w);
    } else {
        v = *(const float4*)((const float*)inp + (size_t)row * D_ + t * 4);
    }
    float s = v.x + v.y + v.z + v.w;
    float ss = v.x * v.x + v.y * v.y + v.z * v.z + v.w * v.w;
#pragma unroll
    for (int o = 32; o > 0; o >>= 1) { s += __shfl_xor(s, o); ss += __shfl_xor(ss, o); }
    __shared__ float red[8];
    if (l == 0) { red[w] = s; red[4 + w] = ss; }
    __syncthreads();
    s = red[0] + red[1] + red[2] + red[3];
    ss = red[4] + red[5] + red[6] + red[7];
    const float mu = s * (1.f / D_);
    const float var = ss * (1.f / D_) - mu * mu;
    const float r = rsqrtf(var + 1e-6f);
    const float4 gg = *(const float4*)(g + t * 4);
    const float4 bb = *(const float4*)(be + t * 4);
    float4 o4;
    o4.x = (v.x - mu) * r * gg.x + bb.x;
    o4.y = (v.y - mu) * r * gg.y + bb.y;
    o4.z = (v.z - mu) * r * gg.z + bb.z;
    o4.w = (v.w - mu) * r * gg.w + bb.w;
    if (OUTBF) {
        ushort4 p;
        p.x = f2bf(o4.x); p.y = f2bf(o4.y); p.z = f2bf(o4.z); p.w = f2bf(o4.w);
        *(ushort4*)((unsigned short*)outp + (size_t)row * D_ + t * 4) = p;
    } else {
        *(float4*)((float*)outp + (size_t)row * D_ + t * 4) = o4;
    }
}

// ---------------------------------------------------------------------------
extern "C" void kernel_launch(void* const* d_in, const int* in_sizes, int n_in,
                              void* d_out, int out_size, void* d_ws, size_t ws_size,
                              hipStream_t stream)
{
    (void)in_sizes; (void)n_in; (void)out_size;
    const float* x     = (const float*)d_in[0];
    const float* Wq    = (const float*)d_in[1];
    const float* bq    = (const float*)d_in[2];
    const float* Wk    = (const float*)d_in[3];
    const float* bk    = (const float*)d_in[4];
    const float* Wv    = (const float*)d_in[5];
    const float* bv    = (const float*)d_in[6];
    const float* Wo    = (const float*)d_in[7];
    const float* bo    = (const float*)d_in[8];
    const float* omega = (const float*)d_in[9];
    const float* W1    = (const float*)d_in[10];
    const float* b1    = (const float*)d_in[11];
    const float* W2    = (const float*)d_in[12];
    const float* b2    = (const float*)d_in[13];
    const float* g1    = (const float*)d_in[14];
    const float* be1   = (const float*)d_in[15];
    const float* g2    = (const float*)d_in[16];
    const float* be2   = (const float*)d_in[17];
    float* out = (float*)d_out;

    const size_t ACT = (size_t)BS_ * D_;
    unsigned short* slotQ = (unsigned short*)d_ws;
    unsigned short* slotK = slotQ + ACT;
    unsigned short* slotV = slotK + ACT;
    float* kvp = (float*)(slotV + ACT);
    unsigned short* kvT = (unsigned short*)(kvp + (size_t)8 * 64 * 80 * 128);
    unsigned short* Wqkvt = kvT + (size_t)64 * 80 * 128;
    unsigned short* Wot = Wqkvt + (size_t)3 * D_ * D_;
    unsigned short* W1t = Wot + (size_t)D_ * D_;
    unsigned short* W2t = W1t + (size_t)D_ * DFF_;
    unsigned short* wsEnd = W2t + (size_t)DFF_ * D_;

    const size_t fixedBytes = (size_t)((char*)wsEnd - (char*)d_ws);
    char* cur = (char*)wsEnd;

    const bool useFused = ws_size >= fixedBytes + ACT * 2;
    unsigned short* xbf = nullptr;
    if (useFused) { xbf = (unsigned short*)cur; cur += ACT * 2; }
    const size_t usedBytes = (size_t)(cur - (char*)d_ws);

    int nch;
    unsigned short* ffn1;
    if (ws_size >= usedBytes + (size_t)BS_ * DFF_ * 2) {
        nch = 1;  ffn1 = (unsigned short*)cur;
    } else if (ws_size >= usedBytes + (size_t)(BS_ / 2) * DFF_ * 2) {
        nch = 2;  ffn1 = (unsigned short*)cur;
    } else {
        nch = 4;  ffn1 = slotK;
    }

    unsigned short* attn = slotK;
    unsigned short* tmp1 = slotV;
    unsigned short* out1 = slotQ;
    unsigned short* tmp2 = slotV;

    // 1. weights -> bf16 transposed (Wq/Wk/Wv concatenated along n)
    wconv_kernel<<<dim3(D_ / 32, D_ / 32), 256, 0, stream>>>(Wq, Wqkvt, D_, D_);
    wconv_kernel<<<dim3(D_ / 32, D_ / 32), 256, 0, stream>>>(Wk, Wqkvt + (size_t)D_ * D_, D_, D_);
    wconv_kernel<<<dim3(D_ / 32, D_ / 32), 256, 0, stream>>>(Wv, Wqkvt + (size_t)2 * D_ * D_, D_, D_);
    wconv_kernel<<<dim3(D_ / 32, D_ / 32), 256, 0, stream>>>(Wo, Wot, D_, D_);
    wconv_kernel<<<dim3(DFF_ / 32, D_ / 32), 256, 0, stream>>>(W1, W1t, D_, DFF_);
    wconv_kernel<<<dim3(D_ / 32, DFF_ / 32), 256, 0, stream>>>(W2, W2t, DFF_, D_);

    // 2. Q,K,V projections
    if (useFused) {
        x2bf_kernel<<<dim3(BS_ * D_ / 2048), 256, 0, stream>>>(x, xbf);
        qkv_gemm_kernel<<<dim3(3 * D_ / 128, BS_ / 128), 256, 0, stream>>>(
            xbf, Wqkvt, bq, bk, bv, slotQ, slotK, slotV);
    } else {
        gemm_kernel<0, true, true, false><<<dim3(D_ / 128, BS_ / 128), 256, 0, stream>>>(x, Wqkvt, bq, nullptr, slotQ, D_, D_);
        gemm_kernel<0, true, true, false><<<dim3(D_ / 128, BS_ / 128), 256, 0, stream>>>(x, Wqkvt + (size_t)D_ * D_, bk, nullptr, slotK, D_, D_);
        gemm_kernel<0, true, true, false><<<dim3(D_ / 128, BS_ / 128), 256, 0, stream>>>(x, Wqkvt + (size_t)2 * D_ * D_, bv, nullptr, slotV, D_, D_);
    }

    // 3. phi(k) -> kvT_aug partials -> reduce to bf16
    kv_mfma_kernel<<<dim3(64, 8), 256, 0, stream>>>(slotK, slotV, omega, kvp);
    kvt_reduce_kernel<<<dim3(2560), 256, 0, stream>>>(kvp, kvT);

    // 4. phi(q) -> normalized attention (bf16, overwrites k slot)
    attn_mfma_kernel<<<dim3(64, 32), 256, 0, stream>>>(slotQ, omega, kvT, attn);

    // 5. Wo projection + residual(x f32) -> tmp1; LN -> out1
    gemm_kernel<1, false, true, false><<<dim3(D_ / 128, BS_ / 128), 256, 0, stream>>>(attn, Wot, bo, x, tmp1, D_, D_);
    layernorm_kernel<true, true><<<dim3(BS_), 256, 0, stream>>>(tmp1, g1, be1, out1);

    // 6. FFN in nch row-chunks: elu(out1@W1+b1) @W2+b2+out1
    const int rows = BS_ / nch;
    for (int c = 0; c < nch; ++c) {
        const size_t off = (size_t)c * rows * D_;
        gemm_kernel<2, false, true, false><<<dim3(DFF_ / 128, rows / 128), 256, 0, stream>>>(
            out1 + off, W1t, b1, nullptr, ffn1, DFF_, D_);
        gemm_kernel<1, false, true, true><<<dim3(D_ / 128, rows / 128), 256, 0, stream>>>(
            ffn1, W2t, b2, out1 + off, tmp2 + off, D_, DFF_);
    }

    // 7. LN2 -> out (f32)
    layernorm_kernel<true, false><<<dim3(BS_), 256, 0, stream>>>(tmp2, g2, be2, out);
}

// Round 13
// 641.148 us; speedup vs baseline: 1.3217x; 1.0329x over previous
//
#include <hip/hip_runtime.h>
#include <hip/hip_bf16.h>
#include <math.h>

#define B_   4
#define S_   4096
#define D_   1024
#define H_   16
#define M_   128
#define DH_  64
#define DFF_ 4096
#define BS_  (B_*S_)   // 16384 rows

typedef float  f32x4  __attribute__((ext_vector_type(4)));
typedef __bf16 bf16x8 __attribute__((ext_vector_type(8)));

__device__ __forceinline__ unsigned short f2bf(float f) {
    unsigned int u = __float_as_uint(f);
    u += 0x7FFFu + ((u >> 16) & 1u);     // round-to-nearest-even
    return (unsigned short)(u >> 16);
}
__device__ __forceinline__ float bf2f(unsigned short u) {
    return __uint_as_float((unsigned int)u << 16);
}

typedef __attribute__((address_space(1))) void void_g;
typedef __attribute__((address_space(3))) void void_l;
__device__ __forceinline__ void gl16(const void* g, void* l) {
    __builtin_amdgcn_global_load_lds((const void_g*)g, (void_l*)l, 16, 0, 0);
}

#define QSCALE    0.35355339059327373f   // DH^-0.25
#define QSCALE2   0.125f                 // DH^-0.5
#define INVSQRTM  0.08838834764831845f   // 1/sqrt(128)

// ---------------------------------------------------------------------------
// Weight convert + transpose:  Wt[n][k] = bf16(W[k][n])
// ---------------------------------------------------------------------------
__global__ __launch_bounds__(256) void wconv_kernel(
    const float* __restrict__ W, unsigned short* __restrict__ Wt, int Kd, int Nd)
{
    __shared__ float ts[32][33];
    const int n0 = blockIdx.x * 32, k0 = blockIdx.y * 32;
    const int c = threadIdx.x & 31, rg = threadIdx.x >> 5;
#pragma unroll
    for (int i = 0; i < 4; ++i) {
        int r = rg * 4 + i;
        ts[r][c] = W[(size_t)(k0 + r) * Nd + n0 + c];
    }
    __syncthreads();
#pragma unroll
    for (int i = 0; i < 4; ++i) {
        int r = rg * 4 + i;
        Wt[(size_t)(n0 + r) * Kd + k0 + c] = f2bf(ts[c][r]);
    }
}

// x (f32) -> bf16, 8 elems/thread
__global__ __launch_bounds__(256) void x2bf_kernel(
    const float* __restrict__ in, unsigned short* __restrict__ o)
{
    const size_t i = ((size_t)blockIdx.x * 256 + threadIdx.x) * 8;
    const float4 a = *(const float4*)(in + i);
    const float4 b = *(const float4*)(in + i + 4);
    ushort4 p0, p1;
    p0.x = f2bf(a.x); p0.y = f2bf(a.y); p0.z = f2bf(a.z); p0.w = f2bf(a.w);
    p1.x = f2bf(b.x); p1.y = f2bf(b.y); p1.z = f2bf(b.z); p1.w = f2bf(b.w);
    *(ushort4*)(o + i) = p0;
    *(ushort4*)(o + i + 4) = p1;
}

// ---------------------------------------------------------------------------
// GEMM: C[Mrows,N] = A[Mrows,K] @ Bt[N,K]^T + epilogue
// 128x128 tile, BK=64, 4 waves, mfma_f32_16x16x32_bf16.
// global_load_lds (16B) into LINEAR LDS; content XOR-swizzled via pre-swizzled
// global source (rule 21). EPI: 0 bias, 1 bias+res, 2 bias+ELU.
// (Exact R6 structure - proven config.)
// ---------------------------------------------------------------------------
template<int EPI, bool AF32, bool OBF, bool RBF>
__global__ __launch_bounds__(256, 4) void gemm_kernel(
    const void* __restrict__ Ap,
    const unsigned short* __restrict__ Bt,
    const float* __restrict__ bias,
    const void* __restrict__ resp,
    void* __restrict__ Cp,
    int N, int K)
{
    __shared__ __align__(16) char AsRaw[AF32 ? 32768 : 16384];
    __shared__ __align__(16) char BsRaw[16384];

    const int t = threadIdx.x;
    const int lane = t & 63;
    const int wv = t >> 6;
    const int wr = wv >> 1, wc = wv & 1;
    const int row0 = blockIdx.y * 128;
    const int col0 = blockIdx.x * 128;
    const int l15 = lane & 15, l4 = lane >> 4;

    const int bRow = t >> 3;
    const int bGran = (t & 7) ^ ((t >> 3) & 7);
    const int aRowF = t >> 4;
    const int aGranF = (t & 15) ^ ((t >> 4) & 15);

    f32x4 acc[4][4] = {};

    for (int k0 = 0; k0 < K; k0 += 64) {
#pragma unroll
        for (int r = 0; r < 4; ++r) {
            const int row = r * 32 + bRow;
            gl16(Bt + (size_t)(col0 + row) * K + k0 + bGran * 8,
                 (void*)(BsRaw + r * 4096 + t * 16));
        }
        if (AF32) {
            const float* A = (const float*)Ap;
#pragma unroll
            for (int r = 0; r < 8; ++r) {
                const int row = r * 16 + aRowF;
                gl16(A + (size_t)(row0 + row) * K + k0 + aGranF * 4,
                     (void*)(AsRaw + r * 4096 + t * 16));
            }
        } else {
            const unsigned short* A = (const unsigned short*)Ap;
#pragma unroll
            for (int r = 0; r < 4; ++r) {
                const int row = r * 32 + bRow;
                gl16(A + (size_t)(row0 + row) * K + k0 + bGran * 8,
                     (void*)(AsRaw + r * 4096 + t * 16));
            }
        }
        __syncthreads();

#pragma unroll
        for (int ks = 0; ks < 2; ++ks) {
            bf16x8 af[4], bfv[4];
            if (AF32) {
#pragma unroll
                for (int mi = 0; mi < 4; ++mi) {
                    const int row = wr * 64 + mi * 16 + l15;
                    const int sw = (row & 15) << 4;
                    const float4 x0 = *(const float4*)(AsRaw + row * 256 + ((ks * 128 + l4 * 32) ^ sw));
                    const float4 x1 = *(const float4*)(AsRaw + row * 256 + ((ks * 128 + l4 * 32 + 16) ^ sw));
                    bf16x8 v;
                    v[0] = (__bf16)x0.x; v[1] = (__bf16)x0.y;
                    v[2] = (__bf16)x0.z; v[3] = (__bf16)x0.w;
                    v[4] = (__bf16)x1.x; v[5] = (__bf16)x1.y;
                    v[6] = (__bf16)x1.z; v[7] = (__bf16)x1.w;
                    af[mi] = v;
                }
            } else {
#pragma unroll
                for (int mi = 0; mi < 4; ++mi) {
                    const int row = wr * 64 + mi * 16 + l15;
                    af[mi] = *(const bf16x8*)(AsRaw + row * 128 + ((ks * 64 + l4 * 16) ^ ((row & 7) << 4)));
                }
            }
#pragma unroll
            for (int ni = 0; ni < 4; ++ni) {
                const int row = wc * 64 + ni * 16 + l15;
                bfv[ni] = *(const bf16x8*)(BsRaw + row * 128 + ((ks * 64 + l4 * 16) ^ ((row & 7) << 4)));
            }
#pragma unroll
            for (int mi = 0; mi < 4; ++mi)
#pragma unroll
                for (int ni = 0; ni < 4; ++ni)
                    acc[mi][ni] = __builtin_amdgcn_mfma_f32_16x16x32_bf16(
                        af[mi], bfv[ni], acc[mi][ni], 0, 0, 0);
        }
        __syncthreads();
    }

#pragma unroll
    for (int ni = 0; ni < 4; ++ni) {
        const int col = col0 + wc * 64 + ni * 16 + l15;
        const float bc = bias[col];
#pragma unroll
        for (int mi = 0; mi < 4; ++mi) {
#pragma unroll
            for (int r = 0; r < 4; ++r) {
                const int row = row0 + wr * 64 + mi * 16 + l4 * 4 + r;
                float v = acc[mi][ni][r] + bc;
                if (EPI == 1) {
                    if (RBF) v += bf2f(((const unsigned short*)resp)[(size_t)row * N + col]);
                    else     v += ((const float*)resp)[(size_t)row * N + col];
                }
                if (EPI == 2) v = v > 0.f ? v : expm1f(v);
                if (OBF) ((unsigned short*)Cp)[(size_t)row * N + col] = f2bf(v);
                else     ((float*)Cp)[(size_t)row * N + col] = v;
            }
        }
    }
}

// ---------------------------------------------------------------------------
// Fused QKV GEMM (exact R6 form, identity block mapping - proven 104 us).
// grid (24, 128).
// ---------------------------------------------------------------------------
__global__ __launch_bounds__(256, 4) void qkv_gemm_kernel(
    const unsigned short* __restrict__ A,     // xbf [BS_, 1024]
    const unsigned short* __restrict__ Bt,    // Wqkvt [3072][1024]
    const float* __restrict__ bq, const float* __restrict__ bk,
    const float* __restrict__ bv,
    unsigned short* __restrict__ outQ, unsigned short* __restrict__ outK,
    unsigned short* __restrict__ outV)
{
    const int K = 1024;
    __shared__ __align__(16) char AsRaw[16384];
    __shared__ __align__(16) char BsRaw[16384];

    const int t = threadIdx.x;
    const int lane = t & 63;
    const int wv = t >> 6;
    const int wr = wv >> 1, wc = wv & 1;
    const int row0 = blockIdx.y * 128;
    const int col0 = blockIdx.x * 128;
    const int l15 = lane & 15, l4 = lane >> 4;

    const int bRow = t >> 3;
    const int bGran = (t & 7) ^ ((t >> 3) & 7);

    f32x4 acc[4][4] = {};

    for (int k0 = 0; k0 < K; k0 += 64) {
#pragma unroll
        for (int r = 0; r < 4; ++r) {
            const int row = r * 32 + bRow;
            gl16(Bt + (size_t)(col0 + row) * K + k0 + bGran * 8,
                 (void*)(BsRaw + r * 4096 + t * 16));
        }
#pragma unroll
        for (int r = 0; r < 4; ++r) {
            const int row = r * 32 + bRow;
            gl16(A + (size_t)(row0 + row) * K + k0 + bGran * 8,
                 (void*)(AsRaw + r * 4096 + t * 16));
        }
        __syncthreads();

#pragma unroll
        for (int ks = 0; ks < 2; ++ks) {
            bf16x8 af[4], bfv[4];
#pragma unroll
            for (int mi = 0; mi < 4; ++mi) {
                const int row = wr * 64 + mi * 16 + l15;
                af[mi] = *(const bf16x8*)(AsRaw + row * 128 + ((ks * 64 + l4 * 16) ^ ((row & 7) << 4)));
            }
#pragma unroll
            for (int ni = 0; ni < 4; ++ni) {
                const int row = wc * 64 + ni * 16 + l15;
                bfv[ni] = *(const bf16x8*)(BsRaw + row * 128 + ((ks * 64 + l4 * 16) ^ ((row & 7) << 4)));
            }
#pragma unroll
            for (int mi = 0; mi < 4; ++mi)
#pragma unroll
                for (int ni = 0; ni < 4; ++ni)
                    acc[mi][ni] = __builtin_amdgcn_mfma_f32_16x16x32_bf16(
                        af[mi], bfv[ni], acc[mi][ni], 0, 0, 0);
        }
        __syncthreads();
    }

#pragma unroll
    for (int ni = 0; ni < 4; ++ni) {
        const int colg = col0 + wc * 64 + ni * 16 + l15;   // 0..3071
        const int sel = colg >> 10;
        const int colr = colg & 1023;
        const float* bp = (sel == 0) ? bq : (sel == 1) ? bk : bv;
        unsigned short* op = (sel == 0) ? outQ : (sel == 1) ? outK : outV;
        const float bc = bp[colr];
#pragma unroll
        for (int mi = 0; mi < 4; ++mi) {
#pragma unroll
            for (int r = 0; r < 4; ++r) {
                const int row = row0 + wr * 64 + mi * 16 + l4 * 4 + r;
                op[(size_t)row * D_ + colr] = f2bf(acc[mi][ni][r] + bc);
            }
        }
    }
}

// ---------------------------------------------------------------------------
// kv kernel (MFMA): per (bh, chunk of 512 rows), 8 sub-tiles of 64 rows.
// ---------------------------------------------------------------------------
__global__ __launch_bounds__(256) void kv_mfma_kernel(
    const unsigned short* __restrict__ Kmat,
    const unsigned short* __restrict__ Vmat,
    const float* __restrict__ omega,
    float* __restrict__ kvp)
{
    __shared__ unsigned short omegaB[128][72];
    __shared__ union U2 {
        unsigned short kA[64][72];
        unsigned short vT[80 * 64];
    } u2;
    __shared__ unsigned short pk[64][130];
    __shared__ float sqp[256];
    __shared__ float sqk[64];

    const int bh = blockIdx.x, chunk = blockIdx.y;
    const int b = bh >> 4, h = bh & 15;
    const int t = threadIdx.x, l = t & 63, w = t >> 6;
    const int l15 = l & 15, l4 = l >> 4;
    const int srow0 = b * S_ + chunk * 512;

    {
        const int m = t >> 1, d0 = (t & 1) * 32;
        const float* src = omega + m * 64 + d0;
#pragma unroll
        for (int i = 0; i < 8; ++i) {
            float4 v4 = *(const float4*)(src + i * 4);
            ushort4 p;
            p.x = f2bf(v4.x * QSCALE); p.y = f2bf(v4.y * QSCALE);
            p.z = f2bf(v4.z * QSCALE); p.w = f2bf(v4.w * QSCALE);
            *(ushort4*)&omegaB[m][d0 + i * 4] = p;
        }
    }

    f32x4 akv[5][2] = {};

    for (int sub = 0; sub < 8; ++sub) {
        {
            const int r = t >> 2, d0 = (t & 3) * 16;
            const unsigned short* src = Kmat + (size_t)(srow0 + sub * 64 + r) * D_ + h * 64 + d0;
            uint4 v0 = *(const uint4*)src;
            uint4 v1 = *(const uint4*)(src + 8);
            *(uint4*)&u2.kA[r][d0] = v0;
            *(uint4*)&u2.kA[r][d0 + 8] = v1;
            float a = 0.f;
            const unsigned short* pv = (const unsigned short*)&v0;
#pragma unroll
            for (int j = 0; j < 8; ++j) { float f = bf2f(pv[j]); a += f * f; }
            pv = (const unsigned short*)&v1;
#pragma unroll
            for (int j = 0; j < 8; ++j) { float f = bf2f(pv[j]); a += f * f; }
            sqp[t] = a;
        }
        __syncthreads();
        if (t < 64)
            sqk[t] = (sqp[4 * t] + sqp[4 * t + 1] + sqp[4 * t + 2] + sqp[4 * t + 3]) * (QSCALE2 * 0.5f);
        f32x4 a1[8] = {};
#pragma unroll
        for (int ks = 0; ks < 2; ++ks) {
            bf16x8 af = *(const bf16x8*)&u2.kA[w * 16 + l15][ks * 32 + l4 * 8];
            bf16x8 bf[8];
#pragma unroll
            for (int ni = 0; ni < 8; ++ni)
                bf[ni] = *(const bf16x8*)&omegaB[ni * 16 + l15][ks * 32 + l4 * 8];
#pragma unroll
            for (int ni = 0; ni < 8; ++ni)
                a1[ni] = __builtin_amdgcn_mfma_f32_16x16x32_bf16(af, bf[ni], a1[ni], 0, 0, 0);
        }
        __syncthreads();
#pragma unroll
        for (int ni = 0; ni < 8; ++ni)
#pragma unroll
            for (int r = 0; r < 4; ++r) {
                int row = w * 16 + l4 * 4 + r;
                float p = expf(a1[ni][r] - sqk[row]) * INVSQRTM + 1e-6f;
                pk[row][ni * 16 + l15] = f2bf(p);
            }
        {
            const int s = t >> 2, d0 = (t & 3) * 16;
            const unsigned short* src = Vmat + (size_t)(srow0 + sub * 64 + s) * D_ + h * 64 + d0;
            uint4 v0 = *(const uint4*)src;
            uint4 v1 = *(const uint4*)(src + 8);
            unsigned short tmp[16];
            *(uint4*)&tmp[0] = v0; *(uint4*)&tmp[8] = v1;
            char* vb = (char*)u2.vT;
#pragma unroll
            for (int j = 0; j < 16; ++j) {
                int d = d0 + j;
                int byte = (d * 128 + s * 2) ^ ((d & 7) << 4);
                *(unsigned short*)(vb + byte) = tmp[j];
            }
        }
        if (t < 128) {
            int row = 64 + (t >> 3), s0 = (t & 7) * 8;
            unsigned short val = (row == 64) ? (unsigned short)0x3F80 : (unsigned short)0;
            char* vb = (char*)u2.vT;
#pragma unroll
            for (int j = 0; j < 8; ++j) {
                int byte = (row * 128 + (s0 + j) * 2) ^ ((row & 7) << 4);
                *(unsigned short*)(vb + byte) = val;
            }
        }
        __syncthreads();
#pragma unroll
        for (int ks = 0; ks < 2; ++ks) {
            bf16x8 af[5];
            const char* vb = (const char*)u2.vT;
#pragma unroll
            for (int at = 0; at < 5; ++at) {
                int d = at * 16 + l15;
                int byte = (d * 128 + (ks * 32 + l4 * 8) * 2) ^ ((d & 7) << 4);
                af[at] = *(const bf16x8*)(vb + byte);
            }
            bf16x8 bfr[2];
#pragma unroll
            for (int nt = 0; nt < 2; ++nt) {
                unsigned short tmp[8];
#pragma unroll
                for (int j = 0; j < 8; ++j)
                    tmp[j] = pk[ks * 32 + l4 * 8 + j][w * 32 + nt * 16 + l15];
                bfr[nt] = *(const bf16x8*)tmp;
            }
#pragma unroll
            for (int at = 0; at < 5; ++at)
#pragma unroll
                for (int nt = 0; nt < 2; ++nt)
                    akv[at][nt] = __builtin_amdgcn_mfma_f32_16x16x32_bf16(af[at], bfr[nt], akv[at][nt], 0, 0, 0);
        }
        __syncthreads();
    }

    const size_t base = ((size_t)chunk * 64 + bh) * (80 * 128);
#pragma unroll
    for (int at = 0; at < 5; ++at)
#pragma unroll
        for (int nt = 0; nt < 2; ++nt)
#pragma unroll
            for (int r = 0; r < 4; ++r) {
                int row = at * 16 + l4 * 4 + r;
                int col = w * 32 + nt * 16 + l15;
                kvp[base + (size_t)row * 128 + col] = akv[at][nt][r];
            }
}

__global__ __launch_bounds__(256) void kvt_reduce_kernel(
    const float* __restrict__ kvp, unsigned short* __restrict__ kvT)
{
    const int idx = blockIdx.x * 256 + threadIdx.x;
    const int NKV = 64 * 80 * 128;
    float s = 0.f;
#pragma unroll
    for (int c = 0; c < 8; ++c) s += kvp[(size_t)c * NKV + idx];
    kvT[idx] = f2bf(s);
}

// ---------------------------------------------------------------------------
// attn kernel (MFMA): per (bh, 128-row tile).
// ---------------------------------------------------------------------------
__global__ __launch_bounds__(256) void attn_mfma_kernel(
    const unsigned short* __restrict__ Qmat,
    const float* __restrict__ omega,
    const unsigned short* __restrict__ kvT,
    unsigned short* __restrict__ attn)
{
    __shared__ union U {
        struct { unsigned short omegaB[128][72]; unsigned short qA[128][72]; } s1;
        struct { unsigned short pq[128][136]; } s2;
    } u;
    __shared__ unsigned short kvB[80][136];
    __shared__ float sqp[256];
    __shared__ float sqr[128];
    __shared__ float zden[128];

    const int bh = blockIdx.x, sc = blockIdx.y;
    const int b = bh >> 4, h = bh & 15;
    const int t = threadIdx.x, l = t & 63, w = t >> 6;
    const int l15 = l & 15, l4 = l >> 4;
    const int srow0 = b * S_ + sc * 128;

    {
        const int m = t >> 1, d0 = (t & 1) * 32;
        const float* src = omega + m * 64 + d0;
#pragma unroll
        for (int i = 0; i < 8; ++i) {
            float4 v4 = *(const float4*)(src + i * 4);
            ushort4 p;
            p.x = f2bf(v4.x * QSCALE); p.y = f2bf(v4.y * QSCALE);
            p.z = f2bf(v4.z * QSCALE); p.w = f2bf(v4.w * QSCALE);
            *(ushort4*)&u.s1.omegaB[m][d0 + i * 4] = p;
        }
    }
    if (t < 160) {
        const int rr = t >> 1, c0 = (t & 1) * 64;
        const uint4* src = (const uint4*)(kvT + ((size_t)bh * 80 + rr) * 128 + c0);
#pragma unroll
        for (int i = 0; i < 8; ++i)
            *(uint4*)&kvB[rr][c0 + i * 8] = src[i];
    }
    {
        const int r = t >> 1, d0 = (t & 1) * 32;
        const unsigned short* src = Qmat + (size_t)(srow0 + r) * D_ + h * 64 + d0;
        float a = 0.f;
#pragma unroll
        for (int i = 0; i < 4; ++i) {
            uint4 v8 = *(const uint4*)(src + i * 8);
            *(uint4*)&u.s1.qA[r][d0 + i * 8] = v8;
            const unsigned short* pv = (const unsigned short*)&v8;
#pragma unroll
            for (int j = 0; j < 8; ++j) { float f = bf2f(pv[j]); a += f * f; }
        }
        sqp[t] = a;
    }
    __syncthreads();
    if (t < 128) sqr[t] = (sqp[2 * t] + sqp[2 * t + 1]) * (QSCALE2 * 0.5f);

    f32x4 acc1[2][8] = {};
#pragma unroll
    for (int ks = 0; ks < 2; ++ks) {
        bf16x8 af[2], bf[8];
#pragma unroll
        for (int mi = 0; mi < 2; ++mi)
            af[mi] = *(const bf16x8*)&u.s1.qA[w * 32 + mi * 16 + l15][ks * 32 + l4 * 8];
#pragma unroll
        for (int ni = 0; ni < 8; ++ni)
            bf[ni] = *(const bf16x8*)&u.s1.omegaB[ni * 16 + l15][ks * 32 + l4 * 8];
#pragma unroll
        for (int mi = 0; mi < 2; ++mi)
#pragma unroll
            for (int ni = 0; ni < 8; ++ni)
                acc1[mi][ni] = __builtin_amdgcn_mfma_f32_16x16x32_bf16(af[mi], bf[ni], acc1[mi][ni], 0, 0, 0);
    }
    __syncthreads();

#pragma unroll
    for (int mi = 0; mi < 2; ++mi)
#pragma unroll
        for (int ni = 0; ni < 8; ++ni)
#pragma unroll
            for (int r = 0; r < 4; ++r) {
                int row = w * 32 + mi * 16 + l4 * 4 + r;
                float p = expf(acc1[mi][ni][r] - sqr[row]) * INVSQRTM + 1e-6f;
                u.s2.pq[row][ni * 16 + l15] = f2bf(p);
            }
    __syncthreads();

    f32x4 acc2[2][5] = {};
#pragma unroll
    for (int ks = 0; ks < 4; ++ks) {
        bf16x8 af[2], bf[5];
#pragma unroll
        for (int mi = 0; mi < 2; ++mi)
            af[mi] = *(const bf16x8*)&u.s2.pq[w * 32 + mi * 16 + l15][ks * 32 + l4 * 8];
#pragma unroll
        for (int ni = 0; ni < 5; ++ni)
            bf[ni] = *(const bf16x8*)&kvB[ni * 16 + l15][ks * 32 + l4 * 8];
#pragma unroll
        for (int mi = 0; mi < 2; ++mi)
#pragma unroll
            for (int ni = 0; ni < 5; ++ni)
                acc2[mi][ni] = __builtin_amdgcn_mfma_f32_16x16x32_bf16(af[mi], bf[ni], acc2[mi][ni], 0, 0, 0);
    }
    if (l15 == 0) {
#pragma unroll
        for (int mi = 0; mi < 2; ++mi)
#pragma unroll
            for (int r = 0; r < 4; ++r) {
                int row = w * 32 + mi * 16 + l4 * 4 + r;
                zden[row] = 1.f / (acc2[mi][4][r] + 1e-6f);
            }
    }
    __syncthreads();
#pragma unroll
    for (int ni = 0; ni < 4; ++ni)
#pragma unroll
        for (int mi = 0; mi < 2; ++mi)
#pragma unroll
            for (int r = 0; r < 4; ++r) {
                int row = w * 32 + mi * 16 + l4 * 4 + r;
                float o = acc2[mi][ni][r] * zden[row];
                attn[(size_t)(srow0 + row) * D_ + h * 64 + ni * 16 + l15] = f2bf(o);
            }
}

// ---------------------------------------------------------------------------
// LayerNorm over D_=1024, one row per block.
// ---------------------------------------------------------------------------
template<bool INBF, bool OUTBF>
__global__ __launch_bounds__(256) void layernorm_kernel(
    const void* __restrict__ inp, const float* __restrict__ g,
    const float* __restrict__ be, void* __restrict__ outp)
{
    const int row = blockIdx.x;
    const int t = threadIdx.x;
    const int l = t & 63, w = t >> 6;
    float4 v;
    if (INBF) {
        const ushort4 r4 = *(const ushort4*)((const unsigned short*)inp + (size_t)row * D_ + t * 4);
        v.x = bf2f(r4.x); v.y = bf2f(r4.y); v.z = bf2f(r4.z); v.w = bf2f(r4.w);
    } else {
        v = *(const float4*)((const float*)inp + (size_t)row * D_ + t * 4);
    }
    float s = v.x + v.y + v.z + v.w;
    float ss = v.x * v.x + v.y * v.y + v.z * v.z + v.w * v.w;
#pragma unroll
    for (int o = 32; o > 0; o >>= 1) { s += __shfl_xor(s, o); ss += __shfl_xor(ss, o); }
    __shared__ float red[8];
    if (l == 0) { red[w] = s; red[4 + w] = ss; }
    __syncthreads();
    s = red[0] + red[1] + red[2] + red[3];
    ss = red[4] + red[5] + red[6] + red[7];
    const float mu = s * (1.f / D_);
    const float var = ss * (1.f / D_) - mu * mu;
    const float r = rsqrtf(var + 1e-6f);
    const float4 gg = *(const float4*)(g + t * 4);
    const float4 bb = *(const float4*)(be + t * 4);
    float4 o4;
    o4.x = (v.x - mu) * r * gg.x + bb.x;
    o4.y = (v.y - mu) * r * gg.y + bb.y;
    o4.z = (v.z - mu) * r * gg.z + bb.z;
    o4.w = (v.w - mu) * r * gg.w + bb.w;
    if (OUTBF) {
        ushort4 p;
        p.x = f2bf(o4.x); p.y = f2bf(o4.y); p.z = f2bf(o4.z); p.w = f2bf(o4.w);
        *(ushort4*)((unsigned short*)outp + (size_t)row * D_ + t * 4) = p;
    } else {
        *(float4*)((float*)outp + (size_t)row * D_ + t * 4) = o4;
    }
}

// ---------------------------------------------------------------------------
extern "C" void kernel_launch(void* const* d_in, const int* in_sizes, int n_in,
                              void* d_out, int out_size, void* d_ws, size_t ws_size,
                              hipStream_t stream)
{
    (void)in_sizes; (void)n_in; (void)out_size;
    const float* x     = (const float*)d_in[0];
    const float* Wq    = (const float*)d_in[1];
    const float* bq    = (const float*)d_in[2];
    const float* Wk    = (const float*)d_in[3];
    const float* bk    = (const float*)d_in[4];
    const float* Wv    = (const float*)d_in[5];
    const float* bv    = (const float*)d_in[6];
    const float* Wo    = (const float*)d_in[7];
    const float* bo    = (const float*)d_in[8];
    const float* omega = (const float*)d_in[9];
    const float* W1    = (const float*)d_in[10];
    const float* b1    = (const float*)d_in[11];
    const float* W2    = (const float*)d_in[12];
    const float* b2    = (const float*)d_in[13];
    const float* g1    = (const float*)d_in[14];
    const float* be1   = (const float*)d_in[15];
    const float* g2    = (const float*)d_in[16];
    const float* be2   = (const float*)d_in[17];
    float* out = (float*)d_out;

    const size_t ACT = (size_t)BS_ * D_;
    unsigned short* slotQ = (unsigned short*)d_ws;
    unsigned short* slotK = slotQ + ACT;
    unsigned short* slotV = slotK + ACT;
    float* kvp = (float*)(slotV + ACT);
    unsigned short* kvT = (unsigned short*)(kvp + (size_t)8 * 64 * 80 * 128);
    unsigned short* Wqkvt = kvT + (size_t)64 * 80 * 128;
    unsigned short* Wot = Wqkvt + (size_t)3 * D_ * D_;
    unsigned short* W1t = Wot + (size_t)D_ * D_;
    unsigned short* W2t = W1t + (size_t)D_ * DFF_;
    unsigned short* wsEnd = W2t + (size_t)DFF_ * D_;

    const size_t fixedBytes = (size_t)((char*)wsEnd - (char*)d_ws);
    char* cur = (char*)wsEnd;

    const bool useFused = ws_size >= fixedBytes + ACT * 2;
    unsigned short* xbf = nullptr;
    if (useFused) { xbf = (unsigned short*)cur; cur += ACT * 2; }
    const size_t usedBytes = (size_t)(cur - (char*)d_ws);

    // FFN chunking: prefer nch=2 (64 MB ffn1 chunk stays L3-resident between
    // the W1 write and W2 read; R12 showed nch=1's 128 MB chunk over-fetching).
    int nch;
    unsigned short* ffn1;
    if (ws_size >= usedBytes + (size_t)(BS_ / 2) * DFF_ * 2) {
        nch = 2;  ffn1 = (unsigned short*)cur;
    } else {
        nch = 4;  ffn1 = slotK;
    }

    unsigned short* attn = slotK;
    unsigned short* tmp1 = slotV;
    unsigned short* out1 = slotQ;
    unsigned short* tmp2 = slotV;

    // 1. weights -> bf16 transposed (Wq/Wk/Wv concatenated along n)
    wconv_kernel<<<dim3(D_ / 32, D_ / 32), 256, 0, stream>>>(Wq, Wqkvt, D_, D_);
    wconv_kernel<<<dim3(D_ / 32, D_ / 32), 256, 0, stream>>>(Wk, Wqkvt + (size_t)D_ * D_, D_, D_);
    wconv_kernel<<<dim3(D_ / 32, D_ / 32), 256, 0, stream>>>(Wv, Wqkvt + (size_t)2 * D_ * D_, D_, D_);
    wconv_kernel<<<dim3(D_ / 32, D_ / 32), 256, 0, stream>>>(Wo, Wot, D_, D_);
    wconv_kernel<<<dim3(DFF_ / 32, D_ / 32), 256, 0, stream>>>(W1, W1t, D_, DFF_);
    wconv_kernel<<<dim3(D_ / 32, DFF_ / 32), 256, 0, stream>>>(W2, W2t, DFF_, D_);

    // 2. Q,K,V projections
    if (useFused) {
        x2bf_kernel<<<dim3(BS_ * D_ / 2048), 256, 0, stream>>>(x, xbf);
        qkv_gemm_kernel<<<dim3(3 * D_ / 128, BS_ / 128), 256, 0, stream>>>(
            xbf, Wqkvt, bq, bk, bv, slotQ, slotK, slotV);
    } else {
        gemm_kernel<0, true, true, false><<<dim3(D_ / 128, BS_ / 128), 256, 0, stream>>>(x, Wqkvt, bq, nullptr, slotQ, D_, D_);
        gemm_kernel<0, true, true, false><<<dim3(D_ / 128, BS_ / 128), 256, 0, stream>>>(x, Wqkvt + (size_t)D_ * D_, bk, nullptr, slotK, D_, D_);
        gemm_kernel<0, true, true, false><<<dim3(D_ / 128, BS_ / 128), 256, 0, stream>>>(x, Wqkvt + (size_t)2 * D_ * D_, bv, nullptr, slotV, D_, D_);
    }

    // 3. phi(k) -> kvT_aug partials -> reduce to bf16
    kv_mfma_kernel<<<dim3(64, 8), 256, 0, stream>>>(slotK, slotV, omega, kvp);
    kvt_reduce_kernel<<<dim3(2560), 256, 0, stream>>>(kvp, kvT);

    // 4. phi(q) -> normalized attention (bf16, overwrites k slot)
    attn_mfma_kernel<<<dim3(64, 32), 256, 0, stream>>>(slotQ, omega, kvT, attn);

    // 5. Wo projection + residual -> tmp1; LN -> out1
    //    Residual reads xbf (bf16, 32 MB) instead of x (f32, 64 MB) when available.
    if (useFused) {
        gemm_kernel<1, false, true, true><<<dim3(D_ / 128, BS_ / 128), 256, 0, stream>>>(
            attn, Wot, bo, xbf, tmp1, D_, D_);
    } else {
        gemm_kernel<1, false, true, false><<<dim3(D_ / 128, BS_ / 128), 256, 0, stream>>>(
            attn, Wot, bo, x, tmp1, D_, D_);
    }
    layernorm_kernel<true, true><<<dim3(BS_), 256, 0, stream>>>(tmp1, g1, be1, out1);

    // 6. FFN in nch row-chunks: elu(out1@W1+b1) @W2+b2+out1
    const int rows = BS_ / nch;
    for (int c = 0; c < nch; ++c) {
        const size_t off = (size_t)c * rows * D_;
        gemm_kernel<2, false, true, false><<<dim3(DFF_ / 128, rows / 128), 256, 0, stream>>>(
            out1 + off, W1t, b1, nullptr, ffn1, DFF_, D_);
        gemm_kernel<1, false, true, true><<<dim3(D_ / 128, rows / 128), 256, 0, stream>>>(
            ffn1, W2t, b2, out1 + off, tmp2 + off, D_, DFF_);
    }

    // 7. LN2 -> out (f32)
    layernorm_kernel<true, false><<<dim3(BS_), 256, 0, stream>>>(tmp2, g2, be2, out);
}